// Round 7
// baseline (1338.651 us; speedup 1.0000x reference)
//
#include <hip/hip_runtime.h>
#include <hip/hip_bf16.h>
#include <cfloat>
#include <math.h>

#define SEQ    2048
#define HID    4096
#define NHEAD  32
#define NKVH   8
#define HDIM   128
#define QKVN   6144            /* fused projection width: 4096 Q + 1024 K + 1024 V */
#define HEAVY  204
#define RECENT 204
#define SELN   (SEQ - RECENT)   /* 1844 */
#define MCOLS  (SEQ + 1)        /* 2049 */

typedef unsigned short ushortT;
typedef unsigned int uintT;

using bf16x8 = __attribute__((ext_vector_type(8))) short;
using f32x4  = __attribute__((ext_vector_type(4))) float;

// ---------------- helpers ----------------
__device__ __forceinline__ ushortT f2bf(float x) {
  uintT u = __float_as_uint(x);
  uintT r = (u + 0x7fffu + ((u >> 16) & 1u)) >> 16;   // RNE
  return (ushortT)r;
}
__device__ __forceinline__ float bf2f(ushortT h) {
  return __uint_as_float((uintT)h << 16);
}
__device__ __forceinline__ void gload16(const void* g, void* l) {
  __builtin_amdgcn_global_load_lds((const __attribute__((address_space(1))) void*)g,
                                   (__attribute__((address_space(3))) void*)l, 16, 0, 0);
}

// ---------------- RoPE tables (match numpy fp32 pipeline) ----------------
__global__ void rope_tables_k(float* __restrict__ cost, float* __restrict__ sint) {
  int s = blockIdx.x, d = threadIdx.x;
  int f = d & 63;
  float powv = (float)pow(10000.0, (double)f / 64.0);
  float invf = 1.0f / powv;
  float ang  = (float)s * invf;
  cost[s * HDIM + d] = (float)cos((double)ang);
  sint[s * HDIM + d] = (float)sin((double)ang);
}

// ---------------- RoPE apply to Q region of fused buffer, in place ----------------
__global__ void rope_q_k(float* __restrict__ x, const float* __restrict__ cost,
                         const float* __restrict__ sint) {
  int s = blockIdx.x, h = blockIdx.y, d = threadIdx.x;
  float* row = x + (size_t)s * QKVN + h * HDIM;
  float v  = row[d];
  float vp = row[d ^ 64];
  __syncthreads();
  float rot = (d < 64) ? -vp : vp;
  row[d] = v * cost[s * HDIM + d] + rot * sint[s * HDIM + d];
}

// ---------------- RoPE-K + scale + hi/lo split (reads fused, writes khi/klo) --------
__global__ void rope_k_split_k(const float* __restrict__ fused, const float* __restrict__ cost,
                               const float* __restrict__ sint, ushortT* __restrict__ khi,
                               ushortT* __restrict__ klo) {
  int s = blockIdx.x, kh = blockIdx.y, d = threadIdx.x;
  const float* row = fused + (size_t)s * QKVN + 4096 + kh * HDIM;
  float v  = row[d];
  float vp = row[d ^ 64];
  float rot = (d < 64) ? -vp : vp;
  float r = (v * cost[s * HDIM + d] + rot * sint[s * HDIM + d]) * 0.08838834764831845f;
  ushortT hh = f2bf(r);
  size_t o = ((size_t)s * NKVH + kh) * HDIM + d;
  khi[o] = hh;
  klo[o] = f2bf(r - bf2f(hh));
}

// ---------------- fp32 -> bf16 hi/lo split conversion ----------------
__global__ void convert_split_k(const float* __restrict__ src, ushortT* __restrict__ hi,
                                ushortT* __restrict__ lo, int n4) {
  int i = blockIdx.x * blockDim.x + threadIdx.x;
  if (i >= n4) return;
  float4 v = ((const float4*)src)[i];
  ushort4 h, l;
  h.x = f2bf(v.x); l.x = f2bf(v.x - bf2f(h.x));
  h.y = f2bf(v.y); l.y = f2bf(v.y - bf2f(h.y));
  h.z = f2bf(v.z); l.z = f2bf(v.z - bf2f(h.z));
  h.w = f2bf(v.w); l.w = f2bf(v.w - bf2f(h.w));
  ((ushort4*)hi)[i] = h;
  ((ushort4*)lo)[i] = l;
}
// merged Wq|Wk|Wv split into fused layout rows [0,4096)|[4096,5120)|[5120,6144)
__global__ void convert_wqkv_k(const float* __restrict__ Wq, const float* __restrict__ Wk,
                               const float* __restrict__ Wv, ushortT* __restrict__ hi,
                               ushortT* __restrict__ lo) {
  int i = blockIdx.x * 256 + threadIdx.x;      // float4 index
  if (i >= QKVN * HID / 4) return;
  int e = i * 4;
  int row = e >> 12;
  const float* src;
  if (row < 4096)      src = Wq + e;
  else if (row < 5120) src = Wk + (e - (4096 << 12));
  else                 src = Wv + (e - (5120 << 12));
  float4 v = *(const float4*)src;
  ushort4 h, l;
  h.x = f2bf(v.x); l.x = f2bf(v.x - bf2f(h.x));
  h.y = f2bf(v.y); l.y = f2bf(v.y - bf2f(h.y));
  h.z = f2bf(v.z); l.z = f2bf(v.z - bf2f(h.z));
  h.w = f2bf(v.w); l.w = f2bf(v.w - bf2f(h.w));
  ((ushort4*)hi)[i] = h;
  ((ushort4*)lo)[i] = l;
}
__global__ void convert_hi_k(const float* __restrict__ src, ushortT* __restrict__ hi, int n4) {
  int i = blockIdx.x * blockDim.x + threadIdx.x;
  if (i >= n4) return;
  float4 v = ((const float4*)src)[i];
  ushort4 h;
  h.x = f2bf(v.x); h.y = f2bf(v.y); h.z = f2bf(v.z); h.w = f2bf(v.w);
  ((ushort4*)hi)[i] = h;
}
__global__ void fuse_bias_k(const float* __restrict__ bq, const float* __restrict__ bk,
                            const float* __restrict__ bv, float* __restrict__ bias) {
  int i = blockIdx.x * 256 + threadIdx.x;
  if (i < 4096) bias[i] = bq[i];
  else if (i < 5120) bias[i] = bk[i - 4096];
  else if (i < QKVN) bias[i] = bv[i - 5120];
}

// ---------------- V transpose: fused V region fp32 -> vt [NKVH][128][S] bf16 --------
__global__ __launch_bounds__(256) void transpose_v_k(const float* __restrict__ fused,
                                                     ushortT* __restrict__ vt) {
  int g = blockIdx.x * 256 + threadIdx.x;
  int d = g & 127;
  int rest = g >> 7;
  int sblk = rest & (SEQ / 8 - 1);
  int kh = rest >> 8;
  ushortT tmp[8];
#pragma unroll
  for (int i = 0; i < 8; ++i) {
    float v = fused[(size_t)(sblk * 8 + i) * QKVN + 5120 + kh * HDIM + d];
    tmp[i] = f2bf(v);
  }
  ushortT* o = vt + ((size_t)kh * HDIM + d) * SEQ + sblk * 8;
  *(ushort4*)o = *(ushort4*)tmp;
  *(ushort4*)(o + 4) = *(ushort4*)&tmp[4];
}

// ---------------- pipelined bf16 MFMA GEMM (T2 swizzle + T4 counted vmcnt + T5) ------
// C[m][n] = sum_seg sum_k Aseg[m][k]*Bseg[n][k]  (+bias[n]); K=4096 per segment.
// BM=128 BN=256 BK=32; 256 thr = 4 waves (2M x 2N), wave tile 64x128.
// 3 LDS buffers, 2-tile prefetch depth, s_waitcnt vmcnt(6) + raw s_barrier per iter.
// Buffer (t+2)%3 == (t-1)%3: its readers finished before the previous barrier -> no race.
template<int NSEG>
__global__ __launch_bounds__(256, 2) void gemm_pipe_k(
    const ushortT* __restrict__ A0, const ushortT* __restrict__ A1,
    const ushortT* __restrict__ A2, const ushortT* __restrict__ B0,
    const ushortT* __restrict__ B1, const ushortT* __restrict__ B2,
    const float* __restrict__ bias, float* __restrict__ C, int N) {
  __shared__ __align__(16) ushortT lds[3][(128 + 256) * 32];   // A 8KB | B 16KB per buf
  const int t = threadIdx.x, lane = t & 63;
  const int wm = t >> 7, wn = (t >> 6) & 1;
  const int lq = lane & 15, lg = lane >> 4;
  const size_t bm = (size_t)blockIdx.y * 128, bn = (size_t)blockIdx.x * 256;

  // staging decode (fixed per thread): phys 16B-chunk c -> logical (row, slot)
  int rowA[2], slA[2], rowB[4], slB[4];
#pragma unroll
  for (int j = 0; j < 2; ++j) {
    int c = t + j * 256, rp = c >> 3, s3 = (c & 7) ^ (rp & 7);
    rowA[j] = rp * 2 + (s3 >> 2); slA[j] = s3 & 3;
  }
#pragma unroll
  for (int j = 0; j < 4; ++j) {
    int c = t + j * 256, rp = c >> 3, s3 = (c & 7) ^ (rp & 7);
    rowB[j] = rp * 2 + (s3 >> 2); slB[j] = s3 & 3;
  }
  // ds_read byte offsets (swizzled), fixed per thread
  auto swz = [&](int row, int sl) {
    int rp = row >> 1;
    return (rp * 8 + (((((row & 1) << 2) | sl)) ^ (rp & 7))) * 16;
  };
  int offA[4], offB[8];
#pragma unroll
  for (int fa = 0; fa < 4; ++fa) offA[fa] = swz(wm * 64 + fa * 16 + lq, lg);
#pragma unroll
  for (int fb = 0; fb < 8; ++fb) offB[fb] = 8192 + swz(wn * 128 + fb * 16 + lq, lg);

  f32x4 acc[4][8] = {};

  auto stage = [&](int t2) {
    int seg = (NSEG == 3) ? (t2 >> 7) : 0;               // 128 tiles per 4096-K segment
    int k0  = (NSEG == 3) ? ((t2 & 127) << 5) : (t2 << 5);
    const ushortT* As = (seg == 0) ? A0 : (seg == 1) ? A1 : A2;
    const ushortT* Bs = (seg == 0) ? B0 : (seg == 1) ? B1 : B2;
    char* lb = (char*)&lds[t2 % 3][0];
#pragma unroll
    for (int j = 0; j < 2; ++j) {
      int c = t + j * 256;
      gload16(As + (bm + rowA[j]) * (size_t)4096 + k0 + slA[j] * 8, lb + c * 16);
    }
#pragma unroll
    for (int j = 0; j < 4; ++j) {
      int c = t + j * 256;
      gload16(Bs + (bn + rowB[j]) * (size_t)4096 + k0 + slB[j] * 8, lb + 8192 + c * 16);
    }
  };

  const int NT = NSEG * 128;
  stage(0); stage(1);
  asm volatile("s_waitcnt vmcnt(6)" ::: "memory");       // tile 0 resident
  __builtin_amdgcn_s_barrier();
  __builtin_amdgcn_sched_barrier(0);
  for (int kt = 0; kt < NT; ++kt) {
    if (kt + 2 < NT) stage(kt + 2);                      // into buf (kt+2)%3 == (kt-1)%3
    const char* lb = (const char*)&lds[kt % 3][0];
    bf16x8 a[4], b[8];
#pragma unroll
    for (int fa = 0; fa < 4; ++fa) a[fa] = *(const bf16x8*)(lb + offA[fa]);
#pragma unroll
    for (int fb = 0; fb < 8; ++fb) b[fb] = *(const bf16x8*)(lb + offB[fb]);
    __builtin_amdgcn_s_setprio(1);
#pragma unroll
    for (int fa = 0; fa < 4; ++fa)
#pragma unroll
      for (int fb = 0; fb < 8; ++fb)
        acc[fa][fb] = __builtin_amdgcn_mfma_f32_16x16x32_bf16(a[fa], b[fb], acc[fa][fb], 0, 0, 0);
    __builtin_amdgcn_s_setprio(0);
    __builtin_amdgcn_sched_barrier(0);
    if (kt + 2 < NT) { asm volatile("s_waitcnt vmcnt(6)" ::: "memory"); }
    else             { asm volatile("s_waitcnt vmcnt(0)" ::: "memory"); }
    __builtin_amdgcn_s_barrier();
    __builtin_amdgcn_sched_barrier(0);
  }

  const int crow = (lane >> 4) * 4, ccol = lane & 15;
#pragma unroll
  for (int fa = 0; fa < 4; ++fa)
#pragma unroll
    for (int fb = 0; fb < 8; ++fb) {
      size_t col = bn + wn * 128 + fb * 16 + ccol;
      float badd = bias ? bias[col] : 0.0f;
      size_t row = bm + wm * 64 + fa * 16 + crow;
#pragma unroll
      for (int i = 0; i < 4; ++i)
        C[(row + i) * (size_t)N + col] = acc[fa][fb][i] + badd;
    }
}

// ---------------- MFMA flash attention, two-pass, swapped (S^T = K·Q) ----------------
// 1D grid 512 (XCD-chunked: 4 heads per XCD), 256 thr = 4 waves; wave owns 32 q-cols.
// K pre-scaled by 1/sqrt(128) and split hi/lo (3-product fp32-grade scores).
__global__ __launch_bounds__(256, 2) void attn_mfma_k(
    const float* __restrict__ qb, const ushortT* __restrict__ khi,
    const ushortT* __restrict__ klo, const ushortT* __restrict__ vt,
    ushortT* __restrict__ aout_bf, float* __restrict__ cur_scores) {
  const int hw = blockIdx.x;
  const int lid = (hw & 7) * 64 + (hw >> 3);          // 512 % 8 == 0: bijective
  const int h = lid >> 4, kh = h >> 2;
  const int qb0 = (15 - (lid & 15)) * 128;            // big work first within head
  const int t = threadIdx.x, lane = t & 63, wid = t >> 6;
  const int lq = lane & 15, lg = lane >> 4;

  __shared__ __align__(16) ushortT Khi_s[64 * 128];   // chunk-swizzled: c' = c ^ (k&7)
  __shared__ __align__(16) ushortT Klo_s[64 * 128];
  __shared__ __align__(16) ushortT VT_s[128 * 64];    // c' = c ^ (d&7)
  __shared__ __align__(16) ushortT p_s[4][32][72];    // per-wave P [q][k], pad 72
  __shared__ float cur_part[SEQ];

  for (int i = t; i < SEQ; i += 256) cur_part[i] = 0.0f;

  // ---- Q fragments (hi/lo) in registers; 2 q-frags of 16 columns each
  bf16x8 qh[2][4], ql[2][4];
#pragma unroll
  for (int qf = 0; qf < 2; ++qf) {
    const int qrow = qb0 + wid * 32 + qf * 16 + lq;
#pragma unroll
    for (int ds = 0; ds < 4; ++ds) {
      const float* qp = qb + (size_t)qrow * QKVN + h * HDIM + ds * 32 + lg * 8;
      float4 a = *(const float4*)qp, b = *(const float4*)(qp + 4);
      float v[8] = {a.x, a.y, a.z, a.w, b.x, b.y, b.z, b.w};
#pragma unroll
      for (int j = 0; j < 8; ++j) {
        ushortT hh = f2bf(v[j]);
        qh[qf][ds][j] = (short)hh;
        ql[qf][ds][j] = (short)f2bf(v[j] - bf2f(hh));
      }
    }
  }

  const int ntiles = qb0 / 64 + 2;
  const int qmaxw = qb0 + wid * 32 + 31;              // wave's largest q-row
  float m[2] = {-1e30f, -1e30f}, l[2] = {0.0f, 0.0f};

  auto stage_K = [&](int kt) {
#pragma unroll
    for (int r = 0; r < 4; ++r) {
      int cid = r * 256 + t;
      int k = cid >> 4, cp = cid & 15, c = cp ^ (k & 7);
      size_t goff = ((size_t)(kt + k) * NKVH + kh) * HDIM + c * 8;
      gload16(khi + goff, &Khi_s[cid * 8]);
      gload16(klo + goff, &Klo_s[cid * 8]);
    }
  };
  auto stage_V = [&](int kt) {
#pragma unroll
    for (int r = 0; r < 4; ++r) {
      int cid = r * 256 + t;
      int d = cid >> 3, cp = cid & 7, c = cp ^ (d & 7);
      gload16(vt + ((size_t)kh * HDIM + d) * SEQ + kt + c * 8, &VT_s[cid * 8]);
    }
  };
  auto qkt = [&](f32x4 (&acc)[4][2]) {
#pragma unroll
    for (int ds = 0; ds < 4; ++ds)
#pragma unroll
      for (int kf = 0; kf < 4; ++kf) {
        int krow = kf * 16 + lq;
        int cp = (ds * 4 + lg) ^ (krow & 7);
        bf16x8 ah = *(const bf16x8*)&Khi_s[krow * 128 + cp * 8];
        bf16x8 al = *(const bf16x8*)&Klo_s[krow * 128 + cp * 8];
#pragma unroll
        for (int qf = 0; qf < 2; ++qf) {
          acc[kf][qf] = __builtin_amdgcn_mfma_f32_16x16x32_bf16(ah, qh[qf][ds], acc[kf][qf], 0, 0, 0);
          acc[kf][qf] = __builtin_amdgcn_mfma_f32_16x16x32_bf16(ah, ql[qf][ds], acc[kf][qf], 0, 0, 0);
          acc[kf][qf] = __builtin_amdgcn_mfma_f32_16x16x32_bf16(al, qh[qf][ds], acc[kf][qf], 0, 0, 0);
        }
      }
  };

  // ================= PASS 1: row max + denominator =================
  stage_K(0);
  for (int tile = 0; tile < ntiles; ++tile) {
    const int kt = tile * 64;
    __syncthreads();                       // K(t) resident
    const bool active = (kt <= qmaxw);
    f32x4 acc[4][2] = {};
    if (active) qkt(acc);
    __syncthreads();                       // all LDS reads done
    if (tile + 1 < ntiles) stage_K(kt + 64);   // overlaps softmax VALU
    if (active) {
      const bool diag = (kt + 63 > qb0 + wid * 32);
#pragma unroll
      for (int qf = 0; qf < 2; ++qf) {
        const int qrow = qb0 + wid * 32 + qf * 16 + lq;
        if (diag) {
#pragma unroll
          for (int kf = 0; kf < 4; ++kf)
#pragma unroll
            for (int r = 0; r < 4; ++r)
              if (kt + kf * 16 + lg * 4 + r > qrow) acc[kf][qf][r] = -1e30f;
        }
        float tmax = -1e30f;
#pragma unroll
        for (int kf = 0; kf < 4; ++kf)
#pragma unroll
          for (int r = 0; r < 4; ++r) tmax = fmaxf(tmax, acc[kf][qf][r]);
        tmax = fmaxf(tmax, __shfl_xor(tmax, 16));
        tmax = fmaxf(tmax, __shfl_xor(tmax, 32));
        float mnew = fmaxf(m[qf], tmax);
        float ts = 0.0f;
#pragma unroll
        for (int kf = 0; kf < 4; ++kf)
#pragma unroll
          for (int r = 0; r < 4; ++r) ts += __expf(acc[kf][qf][r] - mnew);
        ts += __shfl_xor(ts, 16);
        ts += __shfl_xor(ts, 32);
        l[qf] = l[qf] * __expf(m[qf] - mnew) + ts;
        m[qf] = mnew;
      }
    }
  }

  const float rl0 = 1.0f / l[0], rl1 = 1.0f / l[1];
  f32x4 accO[8][2] = {};

  // ================= PASS 2: p -> cur (fp32) + p_s (bf16) + PV =================
  stage_K(0);
  for (int tile = 0; tile < ntiles; ++tile) {
    const int kt = tile * 64;
    __syncthreads();                       // K(t) resident; PV(t-1) done with VT_s
    stage_V(kt);                           // V(t) flies under QK^T + softmax
    const bool active = (kt <= qmaxw);
    f32x4 acc[4][2] = {};
    if (active) qkt(acc);
    __syncthreads();                       // all K-reads done
    if (tile + 1 < ntiles) stage_K(kt + 64);   // overlaps softmax VALU
    if (active) {
      const bool diag = (kt + 63 > qb0 + wid * 32);
      f32x4 csum[4];                       // per-key q-sums (over both qfrags)
#pragma unroll
      for (int kf = 0; kf < 4; ++kf)
#pragma unroll
        for (int r = 0; r < 4; ++r) csum[kf][r] = 0.0f;
#pragma unroll
      for (int qf = 0; qf < 2; ++qf) {
        const int qrow = qb0 + wid * 32 + qf * 16 + lq;
        const float rl = (qf == 0) ? rl0 : rl1;
        const float mq = m[qf];
        if (diag) {
#pragma unroll
          for (int kf = 0; kf < 4; ++kf)
#pragma unroll
            for (int r = 0; r < 4; ++r)
              if (kt + kf * 16 + lg * 4 + r > qrow) acc[kf][qf][r] = -1e30f;
        }
#pragma unroll
        for (int kf = 0; kf < 4; ++kf) {
          ushortT pk[4];
#pragma unroll
          for (int r = 0; r < 4; ++r) {
            float p = __expf(acc[kf][qf][r] - mq) * rl;
            csum[kf][r] += p;
            pk[r] = f2bf(p);
          }
          *(ushort4*)&p_s[wid][qf * 16 + lq][kf * 16 + lg * 4] = *(ushort4*)pk;
        }
      }
#pragma unroll
      for (int kf = 0; kf < 4; ++kf)
#pragma unroll
        for (int r = 0; r < 4; ++r) {
          float v = csum[kf][r];
          v += __shfl_xor(v, 1); v += __shfl_xor(v, 2);
          v += __shfl_xor(v, 4); v += __shfl_xor(v, 8);
          csum[kf][r] = v;                 // q-sum for key kf*16+lg*4+r
        }
      {
        float sel = csum[0][0];
#pragma unroll
        for (int i = 1; i < 16; ++i) {
          float v = csum[i >> 2][i & 3];
          sel = (lq == i) ? v : sel;
        }
        int ksel = (lq >> 2) * 16 + lg * 4 + (lq & 3);   // 64 distinct keys per wave
        atomicAdd(&cur_part[kt + ksel], sel);
      }
    }
    __syncthreads();                       // p_s visible; V(t) resident
    if (active) {
#pragma unroll
      for (int ks = 0; ks < 2; ++ks) {
        bf16x8 pb[2];
#pragma unroll
        for (int qf = 0; qf < 2; ++qf)
          pb[qf] = *(const bf16x8*)&p_s[wid][qf * 16 + lq][ks * 32 + lg * 8];
#pragma unroll
        for (int fa = 0; fa < 8; ++fa) {
          int drow = fa * 16 + lq;
          int cp = (ks * 4 + lg) ^ (drow & 7);
          bf16x8 av = *(const bf16x8*)&VT_s[drow * 64 + cp * 8];
          accO[fa][0] = __builtin_amdgcn_mfma_f32_16x16x32_bf16(av, pb[0], accO[fa][0], 0, 0, 0);
          accO[fa][1] = __builtin_amdgcn_mfma_f32_16x16x32_bf16(av, pb[1], accO[fa][1], 0, 0, 0);
        }
      }
    }
  }

  // flush cur_part -> global (one atomic per key per block)
  __syncthreads();
  const int kmax = qb0 + 128;
  for (int i = t; i < kmax; i += 256)
    atomicAdd(&cur_scores[(size_t)h * SEQ + i], cur_part[i]);

  // epilogue: O^T frag -> aout bf16 [S][NH*128]
#pragma unroll
  for (int qf = 0; qf < 2; ++qf) {
    const int qrow = qb0 + wid * 32 + qf * 16 + lq;
#pragma unroll
    for (int fa = 0; fa < 8; ++fa) {
      ushort4 w4;
      w4.x = f2bf(accO[fa][qf][0]); w4.y = f2bf(accO[fa][qf][1]);
      w4.z = f2bf(accO[fa][qf][2]); w4.w = f2bf(accO[fa][qf][3]);
      *(ushort4*)(aout_bf + (size_t)qrow * (NHEAD * HDIM) + h * HDIM + fa * 16 + lg * 4) = w4;
    }
  }
}

// ---------------- heavy-hitter top-k via exact radix-select -> mask row ----------------
__global__ __launch_bounds__(256) void topk_mask_k(const float* __restrict__ cur,
                                                   float* __restrict__ maskout) {
  const int hh = blockIdx.x;
  const int t = threadIdx.x;
  __shared__ uintT vals[SELN];
  __shared__ uintT hist[256];
  __shared__ uintT sh_prefix, sh_k;
  float* mrow = maskout + (size_t)hh * MCOLS;
  for (int c = t; c < MCOLS; c += 256)
    mrow[c] = (c >= MCOLS - RECENT) ? 1.0f : 0.0f;
  for (int i = t; i < SELN; i += 256)
    vals[i] = __float_as_uint(cur[(size_t)hh * SEQ + i]);
  if (t == 0) { sh_prefix = 0u; sh_k = HEAVY; }
  __syncthreads();
#pragma unroll
  for (int shift = 24; shift >= 0; shift -= 8) {
    if (t < 256) hist[t] = 0;
    __syncthreads();
    const uintT pre = sh_prefix;
    const uintT maskhi = (shift == 24) ? 0u : (0xFFFFFFFFu << (shift + 8));
    for (int i = t; i < SELN; i += 256) {
      uintT v = vals[i];
      if ((v & maskhi) == pre) atomicAdd(&hist[(v >> shift) & 255u], 1u);
    }
    __syncthreads();
    if (t == 0) {
      uintT k = sh_k, cum = 0; int bsel = 0;
      for (int b = 255; b >= 0; --b) {
        if (cum + hist[b] >= k) { bsel = b; break; }
        cum += hist[b];
      }
      sh_prefix = pre | ((uintT)bsel << shift);
      sh_k = k - cum;
    }
    __syncthreads();
  }
  const uintT T = sh_prefix;
  const uintT need = sh_k;
  for (int i = t; i < SELN; i += 256)
    if (vals[i] > T) mrow[i] = 1.0f;
  __syncthreads();
  if (t == 0) {
    uintT taken = 0;
    for (int i = 0; i < SELN && taken < need; ++i)
      if (vals[i] == T) { mrow[i] = 1.0f; ++taken; }
  }
}

extern "C" void kernel_launch(void* const* d_in, const int* in_sizes, int n_in,
                              void* d_out, int out_size, void* d_ws, size_t ws_size,
                              hipStream_t stream) {
  const float* hs = (const float*)d_in[0];
  const float* Wq = (const float*)d_in[1];
  const float* bq = (const float*)d_in[2];
  const float* Wk = (const float*)d_in[3];
  const float* bk = (const float*)d_in[4];
  const float* Wv = (const float*)d_in[5];
  const float* bv = (const float*)d_in[6];
  const float* Wo = (const float*)d_in[7];
  float* out = (float*)d_out;
  float* maskout = out + (size_t)SEQ * HID;

  char* w = (char*)d_ws;
  auto alloc = [&](size_t bytes) { char* p = w; w += (bytes + 255) & ~(size_t)255; return p; };
  float*   fused  = (float*)alloc((size_t)SEQ * QKVN * 4);        // QKV projections
  float*   cost   = (float*)alloc((size_t)SEQ * HDIM * 4);
  float*   sint   = (float*)alloc((size_t)SEQ * HDIM * 4);
  float*   cur    = (float*)alloc((size_t)NHEAD * SEQ * 4);
  float*   biasf  = (float*)alloc((size_t)QKVN * 4);
  ushortT* hshi   = (ushortT*)alloc((size_t)SEQ * HID * 2);
  ushortT* hslo   = (ushortT*)alloc((size_t)SEQ * HID * 2);
  ushortT* whi    = (ushortT*)alloc((size_t)QKVN * HID * 2);
  ushortT* wlo    = (ushortT*)alloc((size_t)QKVN * HID * 2);
  ushortT* wohi   = (ushortT*)alloc((size_t)HID * HID * 2);
  // aliases: consumed-before-written ordering makes these safe
  ushortT* aouthi = hshi;                                  // attn out (after GEMM read hshi)
  ushortT* khi_g  = hslo;                                  // 2048*1024 each
  ushortT* klo_g  = hslo + (size_t)SEQ * NKVH * HDIM;
  ushortT* vt_g   = hslo + (size_t)2 * SEQ * NKVH * HDIM;

  hipLaunchKernelGGL(rope_tables_k, dim3(SEQ), dim3(HDIM), 0, stream, cost, sint);

  {
    int n4;
    n4 = SEQ * HID / 4;
    hipLaunchKernelGGL(convert_split_k, dim3((n4 + 255) / 256), dim3(256), 0, stream, hs, hshi, hslo, n4);
    n4 = QKVN * HID / 4;                      // Wq|Wk|Wv merged split
    hipLaunchKernelGGL(convert_wqkv_k, dim3((n4 + 255) / 256), dim3(256), 0, stream,
                       Wq, Wk, Wv, whi, wlo);
    n4 = HID * HID / 4;
    hipLaunchKernelGGL(convert_hi_k, dim3((n4 + 255) / 256), dim3(256), 0, stream, Wo, wohi, n4);
    hipLaunchKernelGGL(fuse_bias_k, dim3(QKVN / 256), dim3(256), 0, stream, bq, bk, bv, biasf);
  }

  // fused QKV projection: K-extended 3-product (Ahi·Bhi + Ahi·Blo + Alo·Bhi)
  hipLaunchKernelGGL((gemm_pipe_k<3>), dim3(QKVN / 256, SEQ / 128), dim3(256), 0, stream,
                     hshi, hshi, hslo, whi, wlo, whi, biasf, fused, QKVN);

  hipLaunchKernelGGL(rope_q_k, dim3(SEQ, NHEAD), dim3(HDIM), 0, stream, fused, cost, sint);
  hipLaunchKernelGGL(rope_k_split_k, dim3(SEQ, NKVH), dim3(HDIM), 0, stream, fused, cost, sint,
                     khi_g, klo_g);
  hipLaunchKernelGGL(transpose_v_k, dim3(NKVH * HDIM * (SEQ / 8) / 256), dim3(256), 0, stream,
                     fused, vt_g);

  hipMemsetAsync(cur, 0, (size_t)NHEAD * SEQ * sizeof(float), stream);

  hipLaunchKernelGGL(attn_mfma_k, dim3((SEQ / 128) * NHEAD), dim3(256), 0, stream,
                     fused, khi_g, klo_g, vt_g, aouthi, cur);

  // out projection (plain bf16)
  hipLaunchKernelGGL((gemm_pipe_k<1>), dim3(HID / 256, SEQ / 128), dim3(256), 0, stream,
                     aouthi, aouthi, aouthi, wohi, wohi, wohi,
                     (const float*)nullptr, out, HID);

  hipLaunchKernelGGL(topk_mask_k, dim3(NHEAD), dim3(256), 0, stream, cur, maskout);
}

// Round 8
// 768.575 us; speedup vs baseline: 1.7417x; 1.7417x over previous
//
#include <hip/hip_runtime.h>
#include <hip/hip_bf16.h>
#include <cfloat>
#include <math.h>

#define SEQ    2048
#define HID    4096
#define NHEAD  32
#define NKVH   8
#define HDIM   128
#define QKVN   6144            /* fused projection width: 4096 Q + 1024 K + 1024 V */
#define HEAVY  204
#define RECENT 204
#define SELN   (SEQ - RECENT)   /* 1844 */
#define MCOLS  (SEQ + 1)        /* 2049 */

typedef unsigned short ushortT;
typedef unsigned int uintT;

using bf16x8 = __attribute__((ext_vector_type(8))) short;
using f32x4  = __attribute__((ext_vector_type(4))) float;

// ---------------- helpers ----------------
__device__ __forceinline__ ushortT f2bf(float x) {
  uintT u = __float_as_uint(x);
  uintT r = (u + 0x7fffu + ((u >> 16) & 1u)) >> 16;   // RNE
  return (ushortT)r;
}
__device__ __forceinline__ float bf2f(ushortT h) {
  return __uint_as_float((uintT)h << 16);
}
__device__ __forceinline__ void gload16(const void* g, void* l) {
  __builtin_amdgcn_global_load_lds((const __attribute__((address_space(1))) void*)g,
                                   (__attribute__((address_space(3))) void*)l, 16, 0, 0);
}

// ---------------- RoPE tables (match numpy fp32 pipeline) ----------------
__global__ void rope_tables_k(float* __restrict__ cost, float* __restrict__ sint) {
  int s = blockIdx.x, d = threadIdx.x;
  int f = d & 63;
  float powv = (float)pow(10000.0, (double)f / 64.0);
  float invf = 1.0f / powv;
  float ang  = (float)s * invf;
  cost[s * HDIM + d] = (float)cos((double)ang);
  sint[s * HDIM + d] = (float)sin((double)ang);
}

// ---------------- RoPE-K + scale + hi/lo split (reads fused, writes khi/klo) --------
__global__ void rope_k_split_k(const float* __restrict__ fused, const float* __restrict__ cost,
                               const float* __restrict__ sint, ushortT* __restrict__ khi,
                               ushortT* __restrict__ klo) {
  int s = blockIdx.x, kh = blockIdx.y, d = threadIdx.x;
  const float* row = fused + (size_t)s * QKVN + 4096 + kh * HDIM;
  float v  = row[d];
  float vp = row[d ^ 64];
  float rot = (d < 64) ? -vp : vp;
  float r = (v * cost[s * HDIM + d] + rot * sint[s * HDIM + d]) * 0.08838834764831845f;
  ushortT hh = f2bf(r);
  size_t o = ((size_t)s * NKVH + kh) * HDIM + d;
  khi[o] = hh;
  klo[o] = f2bf(r - bf2f(hh));
}

// ---------------- fp32 -> bf16 hi/lo split conversion ----------------
__global__ void convert_split_k(const float* __restrict__ src, ushortT* __restrict__ hi,
                                ushortT* __restrict__ lo, int n4) {
  int i = blockIdx.x * blockDim.x + threadIdx.x;
  if (i >= n4) return;
  float4 v = ((const float4*)src)[i];
  ushort4 h, l;
  h.x = f2bf(v.x); l.x = f2bf(v.x - bf2f(h.x));
  h.y = f2bf(v.y); l.y = f2bf(v.y - bf2f(h.y));
  h.z = f2bf(v.z); l.z = f2bf(v.z - bf2f(h.z));
  h.w = f2bf(v.w); l.w = f2bf(v.w - bf2f(h.w));
  ((ushort4*)hi)[i] = h;
  ((ushort4*)lo)[i] = l;
}
// merged Wq|Wk|Wv split into fused layout rows [0,4096)|[4096,5120)|[5120,6144)
__global__ void convert_wqkv_k(const float* __restrict__ Wq, const float* __restrict__ Wk,
                               const float* __restrict__ Wv, ushortT* __restrict__ hi,
                               ushortT* __restrict__ lo) {
  int i = blockIdx.x * 256 + threadIdx.x;      // float4 index
  if (i >= QKVN * HID / 4) return;
  int e = i * 4;
  int row = e >> 12;
  const float* src;
  if (row < 4096)      src = Wq + e;
  else if (row < 5120) src = Wk + (e - (4096 << 12));
  else                 src = Wv + (e - (5120 << 12));
  float4 v = *(const float4*)src;
  ushort4 h, l;
  h.x = f2bf(v.x); l.x = f2bf(v.x - bf2f(h.x));
  h.y = f2bf(v.y); l.y = f2bf(v.y - bf2f(h.y));
  h.z = f2bf(v.z); l.z = f2bf(v.z - bf2f(h.z));
  h.w = f2bf(v.w); l.w = f2bf(v.w - bf2f(h.w));
  ((ushort4*)hi)[i] = h;
  ((ushort4*)lo)[i] = l;
}
__global__ void convert_hi_k(const float* __restrict__ src, ushortT* __restrict__ hi, int n4) {
  int i = blockIdx.x * blockDim.x + threadIdx.x;
  if (i >= n4) return;
  float4 v = ((const float4*)src)[i];
  ushort4 h;
  h.x = f2bf(v.x); h.y = f2bf(v.y); h.z = f2bf(v.z); h.w = f2bf(v.w);
  ((ushort4*)hi)[i] = h;
}
__global__ void fuse_bias_k(const float* __restrict__ bq, const float* __restrict__ bk,
                            const float* __restrict__ bv, float* __restrict__ bias) {
  int i = blockIdx.x * 256 + threadIdx.x;
  if (i < 4096) bias[i] = bq[i];
  else if (i < 5120) bias[i] = bk[i - 4096];
  else if (i < QKVN) bias[i] = bv[i - 5120];
}

// ---------------- V transpose: fused V region fp32 -> vt [NKVH][128][S] bf16 --------
__global__ __launch_bounds__(256) void transpose_v_k(const float* __restrict__ fused,
                                                     ushortT* __restrict__ vt) {
  int g = blockIdx.x * 256 + threadIdx.x;
  int d = g & 127;
  int rest = g >> 7;
  int sblk = rest & (SEQ / 8 - 1);
  int kh = rest >> 8;
  ushortT tmp[8];
#pragma unroll
  for (int i = 0; i < 8; ++i) {
    float v = fused[(size_t)(sblk * 8 + i) * QKVN + 5120 + kh * HDIM + d];
    tmp[i] = f2bf(v);
  }
  ushortT* o = vt + ((size_t)kh * HDIM + d) * SEQ + sblk * 8;
  *(ushort4*)o = *(ushort4*)tmp;
  *(ushort4*)(o + 4) = *(ushort4*)&tmp[4];
}

// ---------------- bf16 MFMA NT GEMM (split-precision capable, prefetch) ----------------
// Proven R5 structure (909 TF): 128x128 tile, BK=32, 4 waves, natural 2D dispatch.
template<int NPROD>
__global__ __launch_bounds__(256, NPROD == 3 ? 3 : 4) void gemm_mfma_nt(
    const ushortT* __restrict__ Ahi, const ushortT* __restrict__ Alo,
    const ushortT* __restrict__ Bhi, const ushortT* __restrict__ Blo,
    const float* __restrict__ bias, float* __restrict__ C,
    int M, int N, int K) {
  constexpr int NB = (NPROD == 3) ? 2 : 1;
  __shared__ __align__(16) ushortT As[NB][128 * 32];
  __shared__ __align__(16) ushortT Bs[NB][128 * 32];
  const int t = threadIdx.x;
  const int lane = t & 63, wid = t >> 6;
  const int wm = wid >> 1, wn = wid & 1;
  const size_t bm = (size_t)blockIdx.y * 128, bn = (size_t)blockIdx.x * 128;
  f32x4 acc[4][4] = {};
  const int r0 = t >> 2, kc0 = (t & 3) * 8;

  auto stage = [&](int k0) {
    const ushortT* ga = Ahi + (bm + r0) * (size_t)K + k0 + kc0;
    gload16(ga, &As[0][r0 * 32 + kc0]);
    gload16(ga + (size_t)64 * K, &As[0][(r0 + 64) * 32 + kc0]);
    const ushortT* gb = Bhi + (bn + r0) * (size_t)K + k0 + kc0;
    gload16(gb, &Bs[0][r0 * 32 + kc0]);
    gload16(gb + (size_t)64 * K, &Bs[0][(r0 + 64) * 32 + kc0]);
    if constexpr (NPROD == 3) {
      const ushortT* ga2 = Alo + (bm + r0) * (size_t)K + k0 + kc0;
      gload16(ga2, &As[1][r0 * 32 + kc0]);
      gload16(ga2 + (size_t)64 * K, &As[1][(r0 + 64) * 32 + kc0]);
      const ushortT* gb2 = Blo + (bn + r0) * (size_t)K + k0 + kc0;
      gload16(gb2, &Bs[1][r0 * 32 + kc0]);
      gload16(gb2 + (size_t)64 * K, &Bs[1][(r0 + 64) * 32 + kc0]);
    }
  };

  stage(0);
  for (int k0 = 0; k0 < K; k0 += 32) {
    __syncthreads();                 // drain: tile k0 resident in LDS
    const int frow = lane & 15, fk = (lane >> 4) * 8;
    bf16x8 ah[4], bh[4], al[4], bl[4];
#pragma unroll
    for (int f = 0; f < 4; ++f) {
      ah[f] = *(const bf16x8*)&As[0][(wm * 64 + f * 16 + frow) * 32 + fk];
      bh[f] = *(const bf16x8*)&Bs[0][(wn * 64 + f * 16 + frow) * 32 + fk];
      if constexpr (NPROD == 3) {
        al[f] = *(const bf16x8*)&As[1][(wm * 64 + f * 16 + frow) * 32 + fk];
        bl[f] = *(const bf16x8*)&Bs[1][(wn * 64 + f * 16 + frow) * 32 + fk];
      }
    }
    __syncthreads();                 // all waves done reading LDS
    if (k0 + 32 < K) stage(k0 + 32); // prefetch overlaps MFMA below
#pragma unroll
    for (int fr = 0; fr < 4; ++fr)
#pragma unroll
      for (int fc = 0; fc < 4; ++fc) {
        acc[fr][fc] = __builtin_amdgcn_mfma_f32_16x16x32_bf16(ah[fr], bh[fc], acc[fr][fc], 0, 0, 0);
        if constexpr (NPROD == 3) {
          acc[fr][fc] = __builtin_amdgcn_mfma_f32_16x16x32_bf16(ah[fr], bl[fc], acc[fr][fc], 0, 0, 0);
          acc[fr][fc] = __builtin_amdgcn_mfma_f32_16x16x32_bf16(al[fr], bh[fc], acc[fr][fc], 0, 0, 0);
        }
      }
  }
  const int crow = (lane >> 4) * 4, ccol = lane & 15;
#pragma unroll
  for (int fr = 0; fr < 4; ++fr)
#pragma unroll
    for (int fc = 0; fc < 4; ++fc) {
      size_t col = bn + wn * 64 + fc * 16 + ccol;
      float badd = bias ? bias[col] : 0.0f;
#pragma unroll
      for (int i = 0; i < 4; ++i) {
        size_t row = bm + wm * 64 + fr * 16 + crow + i;
        C[row * (size_t)N + col] = acc[fr][fc][i] + badd;
      }
    }
}

// ---------------- MFMA flash attention, two-pass, swapped (S^T = K·Q) ----------------
// 1D grid 512 (XCD-chunked: 4 heads per XCD), 256 thr = 4 waves; wave owns 32 q-cols.
// K pre-scaled by 1/sqrt(128) and split hi/lo (3-product fp32-grade scores).
// RoPE-Q fused into the Q-fragment load (d^64 partner lives in ds^2 registers).
__global__ __launch_bounds__(256, 2) void attn_mfma_k(
    const float* __restrict__ qb, const ushortT* __restrict__ khi,
    const ushortT* __restrict__ klo, const ushortT* __restrict__ vt,
    const float* __restrict__ cost, const float* __restrict__ sint,
    ushortT* __restrict__ aout_bf, float* __restrict__ cur_scores) {
  const int hw = blockIdx.x;
  const int lid = (hw & 7) * 64 + (hw >> 3);          // 512 % 8 == 0: bijective
  const int h = lid >> 4, kh = h >> 2;
  const int qb0 = (15 - (lid & 15)) * 128;            // big work first within head
  const int t = threadIdx.x, lane = t & 63, wid = t >> 6;
  const int lq = lane & 15, lg = lane >> 4;

  __shared__ __align__(16) ushortT Khi_s[64 * 128];   // chunk-swizzled: c' = c ^ (k&7)
  __shared__ __align__(16) ushortT Klo_s[64 * 128];
  __shared__ __align__(16) ushortT VT_s[128 * 64];    // c' = c ^ (d&7)
  __shared__ __align__(16) ushortT p_s[4][32][72];    // per-wave P [q][k], pad 72
  __shared__ float cur_part[SEQ];

  for (int i = t; i < SEQ; i += 256) cur_part[i] = 0.0f;

  // ---- Q fragments (hi/lo) in registers; RoPE applied in-register.
  bf16x8 qh[2][4], ql[2][4];
#pragma unroll
  for (int qf = 0; qf < 2; ++qf) {
    const int qrow = qb0 + wid * 32 + qf * 16 + lq;
    const float* qpb = qb + (size_t)qrow * QKVN + h * HDIM;
    const float* cb = cost + qrow * HDIM;
    const float* sb = sint + qrow * HDIM;
    float vv[4][8];
#pragma unroll
    for (int ds = 0; ds < 4; ++ds) {
      const float* qp = qpb + ds * 32 + lg * 8;
      float4 a = *(const float4*)qp, b = *(const float4*)(qp + 4);
      vv[ds][0] = a.x; vv[ds][1] = a.y; vv[ds][2] = a.z; vv[ds][3] = a.w;
      vv[ds][4] = b.x; vv[ds][5] = b.y; vv[ds][6] = b.z; vv[ds][7] = b.w;
    }
#pragma unroll
    for (int ds = 0; ds < 4; ++ds) {
#pragma unroll
      for (int j = 0; j < 8; ++j) {
        int d = ds * 32 + lg * 8 + j;
        float rot = (ds < 2) ? -vv[ds ^ 2][j] : vv[ds ^ 2][j];
        float r = vv[ds][j] * cb[d] + rot * sb[d];
        ushortT hh = f2bf(r);
        qh[qf][ds][j] = (short)hh;
        ql[qf][ds][j] = (short)f2bf(r - bf2f(hh));
      }
    }
  }

  const int ntiles = qb0 / 64 + 2;
  const int qmaxw = qb0 + wid * 32 + 31;              // wave's largest q-row
  float m[2] = {-1e30f, -1e30f}, l[2] = {0.0f, 0.0f};

  auto stage_K = [&](int kt) {
#pragma unroll
    for (int r = 0; r < 4; ++r) {
      int cid = r * 256 + t;
      int k = cid >> 4, cp = cid & 15, c = cp ^ (k & 7);
      size_t goff = ((size_t)(kt + k) * NKVH + kh) * HDIM + c * 8;
      gload16(khi + goff, &Khi_s[cid * 8]);
      gload16(klo + goff, &Klo_s[cid * 8]);
    }
  };
  auto stage_V = [&](int kt) {
#pragma unroll
    for (int r = 0; r < 4; ++r) {
      int cid = r * 256 + t;
      int d = cid >> 3, cp = cid & 7, c = cp ^ (d & 7);
      gload16(vt + ((size_t)kh * HDIM + d) * SEQ + kt + c * 8, &VT_s[cid * 8]);
    }
  };
  auto qkt = [&](f32x4 (&acc)[4][2]) {
#pragma unroll
    for (int ds = 0; ds < 4; ++ds)
#pragma unroll
      for (int kf = 0; kf < 4; ++kf) {
        int krow = kf * 16 + lq;
        int cp = (ds * 4 + lg) ^ (krow & 7);
        bf16x8 ah = *(const bf16x8*)&Khi_s[krow * 128 + cp * 8];
        bf16x8 al = *(const bf16x8*)&Klo_s[krow * 128 + cp * 8];
#pragma unroll
        for (int qf = 0; qf < 2; ++qf) {
          acc[kf][qf] = __builtin_amdgcn_mfma_f32_16x16x32_bf16(ah, qh[qf][ds], acc[kf][qf], 0, 0, 0);
          acc[kf][qf] = __builtin_amdgcn_mfma_f32_16x16x32_bf16(ah, ql[qf][ds], acc[kf][qf], 0, 0, 0);
          acc[kf][qf] = __builtin_amdgcn_mfma_f32_16x16x32_bf16(al, qh[qf][ds], acc[kf][qf], 0, 0, 0);
        }
      }
  };

  // ================= PASS 1: row max + denominator =================
  stage_K(0);
  for (int tile = 0; tile < ntiles; ++tile) {
    const int kt = tile * 64;
    __syncthreads();                       // K(t) resident
    const bool active = (kt <= qmaxw);
    f32x4 acc[4][2] = {};
    if (active) qkt(acc);
    __syncthreads();                       // all LDS reads done
    if (tile + 1 < ntiles) stage_K(kt + 64);   // overlaps softmax VALU
    if (active) {
      const bool diag = (kt + 63 > qb0 + wid * 32);
#pragma unroll
      for (int qf = 0; qf < 2; ++qf) {
        const int qrow = qb0 + wid * 32 + qf * 16 + lq;
        if (diag) {
#pragma unroll
          for (int kf = 0; kf < 4; ++kf)
#pragma unroll
            for (int r = 0; r < 4; ++r)
              if (kt + kf * 16 + lg * 4 + r > qrow) acc[kf][qf][r] = -1e30f;
        }
        float tmax = -1e30f;
#pragma unroll
        for (int kf = 0; kf < 4; ++kf)
#pragma unroll
          for (int r = 0; r < 4; ++r) tmax = fmaxf(tmax, acc[kf][qf][r]);
        tmax = fmaxf(tmax, __shfl_xor(tmax, 16));
        tmax = fmaxf(tmax, __shfl_xor(tmax, 32));
        float mnew = fmaxf(m[qf], tmax);
        float ts = 0.0f;
#pragma unroll
        for (int kf = 0; kf < 4; ++kf)
#pragma unroll
          for (int r = 0; r < 4; ++r) ts += __expf(acc[kf][qf][r] - mnew);
        ts += __shfl_xor(ts, 16);
        ts += __shfl_xor(ts, 32);
        l[qf] = l[qf] * __expf(m[qf] - mnew) + ts;
        m[qf] = mnew;
      }
    }
  }

  const float rl0 = 1.0f / l[0], rl1 = 1.0f / l[1];
  f32x4 accO[8][2] = {};

  // ================= PASS 2: p -> cur (fp32) + p_s (bf16) + PV =================
  stage_K(0);
  for (int tile = 0; tile < ntiles; ++tile) {
    const int kt = tile * 64;
    __syncthreads();                       // K(t) resident; PV(t-1) done with VT_s
    stage_V(kt);                           // V(t) flies under QK^T + softmax
    const bool active = (kt <= qmaxw);
    f32x4 acc[4][2] = {};
    if (active) qkt(acc);
    __syncthreads();                       // all K-reads done
    if (tile + 1 < ntiles) stage_K(kt + 64);   // overlaps softmax VALU
    if (active) {
      const bool diag = (kt + 63 > qb0 + wid * 32);
      f32x4 csum[4];                       // per-key q-sums (over both qfrags)
#pragma unroll
      for (int kf = 0; kf < 4; ++kf)
#pragma unroll
        for (int r = 0; r < 4; ++r) csum[kf][r] = 0.0f;
#pragma unroll
      for (int qf = 0; qf < 2; ++qf) {
        const int qrow = qb0 + wid * 32 + qf * 16 + lq;
        const float rl = (qf == 0) ? rl0 : rl1;
        const float mq = m[qf];
        if (diag) {
#pragma unroll
          for (int kf = 0; kf < 4; ++kf)
#pragma unroll
            for (int r = 0; r < 4; ++r)
              if (kt + kf * 16 + lg * 4 + r > qrow) acc[kf][qf][r] = -1e30f;
        }
#pragma unroll
        for (int kf = 0; kf < 4; ++kf) {
          ushortT pk[4];
#pragma unroll
          for (int r = 0; r < 4; ++r) {
            float p = __expf(acc[kf][qf][r] - mq) * rl;
            csum[kf][r] += p;
            pk[r] = f2bf(p);
          }
          *(ushort4*)&p_s[wid][qf * 16 + lq][kf * 16 + lg * 4] = *(ushort4*)pk;
        }
      }
#pragma unroll
      for (int kf = 0; kf < 4; ++kf)
#pragma unroll
        for (int r = 0; r < 4; ++r) {
          float v = csum[kf][r];
          v += __shfl_xor(v, 1); v += __shfl_xor(v, 2);
          v += __shfl_xor(v, 4); v += __shfl_xor(v, 8);
          csum[kf][r] = v;                 // q-sum for key kf*16+lg*4+r
        }
      {
        float sel = csum[0][0];
#pragma unroll
        for (int i = 1; i < 16; ++i) {
          float v = csum[i >> 2][i & 3];
          sel = (lq == i) ? v : sel;
        }
        int ksel = (lq >> 2) * 16 + lg * 4 + (lq & 3);   // 64 distinct keys per wave
        atomicAdd(&cur_part[kt + ksel], sel);
      }
    }
    __syncthreads();                       // p_s visible; V(t) resident
    if (active) {
#pragma unroll
      for (int ks = 0; ks < 2; ++ks) {
        bf16x8 pb[2];
#pragma unroll
        for (int qf = 0; qf < 2; ++qf)
          pb[qf] = *(const bf16x8*)&p_s[wid][qf * 16 + lq][ks * 32 + lg * 8];
#pragma unroll
        for (int fa = 0; fa < 8; ++fa) {
          int drow = fa * 16 + lq;
          int cp = (ks * 4 + lg) ^ (drow & 7);
          bf16x8 av = *(const bf16x8*)&VT_s[drow * 64 + cp * 8];
          accO[fa][0] = __builtin_amdgcn_mfma_f32_16x16x32_bf16(av, pb[0], accO[fa][0], 0, 0, 0);
          accO[fa][1] = __builtin_amdgcn_mfma_f32_16x16x32_bf16(av, pb[1], accO[fa][1], 0, 0, 0);
        }
      }
    }
  }

  // flush cur_part -> global (one atomic per key per block)
  __syncthreads();
  const int kmax = qb0 + 128;
  for (int i = t; i < kmax; i += 256)
    atomicAdd(&cur_scores[(size_t)h * SEQ + i], cur_part[i]);

  // epilogue: O^T frag -> aout bf16 [S][NH*128]
#pragma unroll
  for (int qf = 0; qf < 2; ++qf) {
    const int qrow = qb0 + wid * 32 + qf * 16 + lq;
#pragma unroll
    for (int fa = 0; fa < 8; ++fa) {
      ushort4 w4;
      w4.x = f2bf(accO[fa][qf][0]); w4.y = f2bf(accO[fa][qf][1]);
      w4.z = f2bf(accO[fa][qf][2]); w4.w = f2bf(accO[fa][qf][3]);
      *(ushort4*)(aout_bf + (size_t)qrow * (NHEAD * HDIM) + h * HDIM + fa * 16 + lg * 4) = w4;
    }
  }
}

// ---------------- heavy-hitter top-k via exact radix-select -> mask row ----------------
__global__ __launch_bounds__(256) void topk_mask_k(const float* __restrict__ cur,
                                                   float* __restrict__ maskout) {
  const int hh = blockIdx.x;
  const int t = threadIdx.x;
  __shared__ uintT vals[SELN];
  __shared__ uintT hist[256];
  __shared__ uintT sh_prefix, sh_k;
  float* mrow = maskout + (size_t)hh * MCOLS;
  for (int c = t; c < MCOLS; c += 256)
    mrow[c] = (c >= MCOLS - RECENT) ? 1.0f : 0.0f;
  for (int i = t; i < SELN; i += 256)
    vals[i] = __float_as_uint(cur[(size_t)hh * SEQ + i]);
  if (t == 0) { sh_prefix = 0u; sh_k = HEAVY; }
  __syncthreads();
#pragma unroll
  for (int shift = 24; shift >= 0; shift -= 8) {
    if (t < 256) hist[t] = 0;
    __syncthreads();
    const uintT pre = sh_prefix;
    const uintT maskhi = (shift == 24) ? 0u : (0xFFFFFFFFu << (shift + 8));
    for (int i = t; i < SELN; i += 256) {
      uintT v = vals[i];
      if ((v & maskhi) == pre) atomicAdd(&hist[(v >> shift) & 255u], 1u);
    }
    __syncthreads();
    if (t == 0) {
      uintT k = sh_k, cum = 0; int bsel = 0;
      for (int b = 255; b >= 0; --b) {
        if (cum + hist[b] >= k) { bsel = b; break; }
        cum += hist[b];
      }
      sh_prefix = pre | ((uintT)bsel << shift);
      sh_k = k - cum;
    }
    __syncthreads();
  }
  const uintT T = sh_prefix;
  const uintT need = sh_k;
  for (int i = t; i < SELN; i += 256)
    if (vals[i] > T) mrow[i] = 1.0f;
  __syncthreads();
  if (t == 0) {
    uintT taken = 0;
    for (int i = 0; i < SELN && taken < need; ++i)
      if (vals[i] == T) { mrow[i] = 1.0f; ++taken; }
  }
}

extern "C" void kernel_launch(void* const* d_in, const int* in_sizes, int n_in,
                              void* d_out, int out_size, void* d_ws, size_t ws_size,
                              hipStream_t stream) {
  const float* hs = (const float*)d_in[0];
  const float* Wq = (const float*)d_in[1];
  const float* bq = (const float*)d_in[2];
  const float* Wk = (const float*)d_in[3];
  const float* bk = (const float*)d_in[4];
  const float* Wv = (const float*)d_in[5];
  const float* bv = (const float*)d_in[6];
  const float* Wo = (const float*)d_in[7];
  float* out = (float*)d_out;
  float* maskout = out + (size_t)SEQ * HID;

  char* w = (char*)d_ws;
  auto alloc = [&](size_t bytes) { char* p = w; w += (bytes + 255) & ~(size_t)255; return p; };
  float*   fused  = (float*)alloc((size_t)SEQ * QKVN * 4);        // QKV projections
  float*   cost   = (float*)alloc((size_t)SEQ * HDIM * 4);
  float*   sint   = (float*)alloc((size_t)SEQ * HDIM * 4);
  float*   cur    = (float*)alloc((size_t)NHEAD * SEQ * 4);
  float*   biasf  = (float*)alloc((size_t)QKVN * 4);
  ushortT* hshi   = (ushortT*)alloc((size_t)SEQ * HID * 2);
  ushortT* hslo   = (ushortT*)alloc((size_t)SEQ * HID * 2);
  ushortT* whi    = (ushortT*)alloc((size_t)QKVN * HID * 2);
  ushortT* wlo    = (ushortT*)alloc((size_t)QKVN * HID * 2);
  ushortT* wohi   = (ushortT*)alloc((size_t)HID * HID * 2);
  // aliases: consumed-before-written ordering makes these safe
  ushortT* aouthi = hshi;                                  // attn out (after GEMM read hshi)
  ushortT* khi_g  = hslo;                                  // 2048*1024 each
  ushortT* klo_g  = hslo + (size_t)SEQ * NKVH * HDIM;
  ushortT* vt_g   = hslo + (size_t)2 * SEQ * NKVH * HDIM;

  hipLaunchKernelGGL(rope_tables_k, dim3(SEQ), dim3(HDIM), 0, stream, cost, sint);

  {
    int n4;
    n4 = SEQ * HID / 4;
    hipLaunchKernelGGL(convert_split_k, dim3((n4 + 255) / 256), dim3(256), 0, stream, hs, hshi, hslo, n4);
    n4 = QKVN * HID / 4;                      // Wq|Wk|Wv merged split
    hipLaunchKernelGGL(convert_wqkv_k, dim3((n4 + 255) / 256), dim3(256), 0, stream,
                       Wq, Wk, Wv, whi, wlo);
    n4 = HID * HID / 4;
    hipLaunchKernelGGL(convert_hi_k, dim3((n4 + 255) / 256), dim3(256), 0, stream, Wo, wohi, n4);
    hipLaunchKernelGGL(fuse_bias_k, dim3(QKVN / 256), dim3(256), 0, stream, bq, bk, bv, biasf);
  }

  // fused QKV projection (split-bf16, 3-product), natural 2D dispatch
  hipLaunchKernelGGL((gemm_mfma_nt<3>), dim3(QKVN / 128, SEQ / 128), dim3(256), 0, stream,
                     hshi, hslo, whi, wlo, biasf, fused, SEQ, QKVN, HID);

  hipLaunchKernelGGL(rope_k_split_k, dim3(SEQ, NKVH), dim3(HDIM), 0, stream, fused, cost, sint,
                     khi_g, klo_g);
  hipLaunchKernelGGL(transpose_v_k, dim3(NKVH * HDIM * (SEQ / 8) / 256), dim3(256), 0, stream,
                     fused, vt_g);

  hipMemsetAsync(cur, 0, (size_t)NHEAD * SEQ * sizeof(float), stream);

  hipLaunchKernelGGL(attn_mfma_k, dim3((SEQ / 128) * NHEAD), dim3(256), 0, stream,
                     fused, khi_g, klo_g, vt_g, cost, sint, aouthi, cur);

  // out projection (plain bf16), natural 2D dispatch
  hipLaunchKernelGGL((gemm_mfma_nt<1>), dim3(HID / 128, SEQ / 128), dim3(256), 0, stream,
                     aouthi, (const ushortT*)nullptr, wohi, (const ushortT*)nullptr,
                     (const float*)nullptr, out, SEQ, HID, HID);

  hipLaunchKernelGGL(topk_mask_k, dim3(NHEAD), dim3(256), 0, stream, cur, maskout);
}

// Round 9
// 757.756 us; speedup vs baseline: 1.7666x; 1.0143x over previous
//
#include <hip/hip_runtime.h>
#include <hip/hip_bf16.h>
#include <cfloat>
#include <math.h>

#define SEQ    2048
#define HID    4096
#define NHEAD  32
#define NKVH   8
#define HDIM   128
#define QKVN   6144            /* fused projection width: 4096 Q + 1024 K + 1024 V */
#define HEAVY  204
#define RECENT 204
#define SELN   (SEQ - RECENT)   /* 1844 */
#define MCOLS  (SEQ + 1)        /* 2049 */

typedef unsigned short ushortT;
typedef unsigned int uintT;

using bf16x8 = __attribute__((ext_vector_type(8))) short;
using f32x4  = __attribute__((ext_vector_type(4))) float;

// ---------------- helpers ----------------
__device__ __forceinline__ ushortT f2bf(float x) {
  uintT u = __float_as_uint(x);
  uintT r = (u + 0x7fffu + ((u >> 16) & 1u)) >> 16;   // RNE
  return (ushortT)r;
}
__device__ __forceinline__ float bf2f(ushortT h) {
  return __uint_as_float((uintT)h << 16);
}
__device__ __forceinline__ void gload16(const void* g, void* l) {
  __builtin_amdgcn_global_load_lds((const __attribute__((address_space(1))) void*)g,
                                   (__attribute__((address_space(3))) void*)l, 16, 0, 0);
}

// ---------------- RoPE tables (match numpy fp32 pipeline) ----------------
__global__ void rope_tables_k(float* __restrict__ cost, float* __restrict__ sint) {
  int s = blockIdx.x, d = threadIdx.x;
  int f = d & 63;
  float powv = (float)pow(10000.0, (double)f / 64.0);
  float invf = 1.0f / powv;
  float ang  = (float)s * invf;
  cost[s * HDIM + d] = (float)cos((double)ang);
  sint[s * HDIM + d] = (float)sin((double)ang);
}

// ---------------- RoPE-K + scale + hi/lo split (reads fused, writes khi/klo) --------
__global__ void rope_k_split_k(const float* __restrict__ fused, const float* __restrict__ cost,
                               const float* __restrict__ sint, ushortT* __restrict__ khi,
                               ushortT* __restrict__ klo) {
  int s = blockIdx.x, kh = blockIdx.y, d = threadIdx.x;
  const float* row = fused + (size_t)s * QKVN + 4096 + kh * HDIM;
  float v  = row[d];
  float vp = row[d ^ 64];
  float rot = (d < 64) ? -vp : vp;
  float r = (v * cost[s * HDIM + d] + rot * sint[s * HDIM + d]) * 0.08838834764831845f;
  ushortT hh = f2bf(r);
  size_t o = ((size_t)s * NKVH + kh) * HDIM + d;
  khi[o] = hh;
  klo[o] = f2bf(r - bf2f(hh));
}

// ---------------- fp32 -> bf16 hi/lo split conversion ----------------
__global__ void convert_split_k(const float* __restrict__ src, ushortT* __restrict__ hi,
                                ushortT* __restrict__ lo, int n4) {
  int i = blockIdx.x * blockDim.x + threadIdx.x;
  if (i >= n4) return;
  float4 v = ((const float4*)src)[i];
  ushort4 h, l;
  h.x = f2bf(v.x); l.x = f2bf(v.x - bf2f(h.x));
  h.y = f2bf(v.y); l.y = f2bf(v.y - bf2f(h.y));
  h.z = f2bf(v.z); l.z = f2bf(v.z - bf2f(h.z));
  h.w = f2bf(v.w); l.w = f2bf(v.w - bf2f(h.w));
  ((ushort4*)hi)[i] = h;
  ((ushort4*)lo)[i] = l;
}
// merged Wq|Wk|Wv split into fused layout rows [0,4096)|[4096,5120)|[5120,6144)
__global__ void convert_wqkv_k(const float* __restrict__ Wq, const float* __restrict__ Wk,
                               const float* __restrict__ Wv, ushortT* __restrict__ hi,
                               ushortT* __restrict__ lo) {
  int i = blockIdx.x * 256 + threadIdx.x;      // float4 index
  if (i >= QKVN * HID / 4) return;
  int e = i * 4;
  int row = e >> 12;
  const float* src;
  if (row < 4096)      src = Wq + e;
  else if (row < 5120) src = Wk + (e - (4096 << 12));
  else                 src = Wv + (e - (5120 << 12));
  float4 v = *(const float4*)src;
  ushort4 h, l;
  h.x = f2bf(v.x); l.x = f2bf(v.x - bf2f(h.x));
  h.y = f2bf(v.y); l.y = f2bf(v.y - bf2f(h.y));
  h.z = f2bf(v.z); l.z = f2bf(v.z - bf2f(h.z));
  h.w = f2bf(v.w); l.w = f2bf(v.w - bf2f(h.w));
  ((ushort4*)hi)[i] = h;
  ((ushort4*)lo)[i] = l;
}
__global__ void convert_hi_k(const float* __restrict__ src, ushortT* __restrict__ hi, int n4) {
  int i = blockIdx.x * blockDim.x + threadIdx.x;
  if (i >= n4) return;
  float4 v = ((const float4*)src)[i];
  ushort4 h;
  h.x = f2bf(v.x); h.y = f2bf(v.y); h.z = f2bf(v.z); h.w = f2bf(v.w);
  ((ushort4*)hi)[i] = h;
}
__global__ void fuse_bias_k(const float* __restrict__ bq, const float* __restrict__ bk,
                            const float* __restrict__ bv, float* __restrict__ bias) {
  int i = blockIdx.x * 256 + threadIdx.x;
  if (i < 4096) bias[i] = bq[i];
  else if (i < 5120) bias[i] = bk[i - 4096];
  else if (i < QKVN) bias[i] = bv[i - 5120];
}

// ---------------- V transpose: fused V region fp32 -> vt [NKVH][128][S] bf16 --------
__global__ __launch_bounds__(256) void transpose_v_k(const float* __restrict__ fused,
                                                     ushortT* __restrict__ vt) {
  int g = blockIdx.x * 256 + threadIdx.x;
  int d = g & 127;
  int rest = g >> 7;
  int sblk = rest & (SEQ / 8 - 1);
  int kh = rest >> 8;
  ushortT tmp[8];
#pragma unroll
  for (int i = 0; i < 8; ++i) {
    float v = fused[(size_t)(sblk * 8 + i) * QKVN + 5120 + kh * HDIM + d];
    tmp[i] = f2bf(v);
  }
  ushortT* o = vt + ((size_t)kh * HDIM + d) * SEQ + sblk * 8;
  *(ushort4*)o = *(ushort4*)tmp;
  *(ushort4*)(o + 4) = *(ushort4*)&tmp[4];
}

// ---------------- bf16 MFMA NT GEMM (split-precision capable, prefetch) ----------------
// Proven R5 structure (909 TF): 128x128 tile, BK=32, 4 waves, natural 2D dispatch.
// Blocks with bn >= split_cols use 1-product (hi·hi) only: V columns need no split.
template<int NPROD>
__global__ __launch_bounds__(256, NPROD == 3 ? 3 : 4) void gemm_mfma_nt(
    const ushortT* __restrict__ Ahi, const ushortT* __restrict__ Alo,
    const ushortT* __restrict__ Bhi, const ushortT* __restrict__ Blo,
    const float* __restrict__ bias, float* __restrict__ C,
    int M, int N, int K, int split_cols) {
  constexpr int NB = (NPROD == 3) ? 2 : 1;
  __shared__ __align__(16) ushortT As[NB][128 * 32];
  __shared__ __align__(16) ushortT Bs[NB][128 * 32];
  const int t = threadIdx.x;
  const int lane = t & 63, wid = t >> 6;
  const int wm = wid >> 1, wn = wid & 1;
  const size_t bm = (size_t)blockIdx.y * 128, bn = (size_t)blockIdx.x * 128;
  const bool dolo = (NPROD == 3) && ((int)bn < split_cols);
  f32x4 acc[4][4] = {};
  const int r0 = t >> 2, kc0 = (t & 3) * 8;

  auto stage = [&](int k0) {
    const ushortT* ga = Ahi + (bm + r0) * (size_t)K + k0 + kc0;
    gload16(ga, &As[0][r0 * 32 + kc0]);
    gload16(ga + (size_t)64 * K, &As[0][(r0 + 64) * 32 + kc0]);
    const ushortT* gb = Bhi + (bn + r0) * (size_t)K + k0 + kc0;
    gload16(gb, &Bs[0][r0 * 32 + kc0]);
    gload16(gb + (size_t)64 * K, &Bs[0][(r0 + 64) * 32 + kc0]);
    if constexpr (NPROD == 3) {
      if (dolo) {
        const ushortT* ga2 = Alo + (bm + r0) * (size_t)K + k0 + kc0;
        gload16(ga2, &As[1][r0 * 32 + kc0]);
        gload16(ga2 + (size_t)64 * K, &As[1][(r0 + 64) * 32 + kc0]);
        const ushortT* gb2 = Blo + (bn + r0) * (size_t)K + k0 + kc0;
        gload16(gb2, &Bs[1][r0 * 32 + kc0]);
        gload16(gb2 + (size_t)64 * K, &Bs[1][(r0 + 64) * 32 + kc0]);
      }
    }
  };

  stage(0);
  for (int k0 = 0; k0 < K; k0 += 32) {
    __syncthreads();                 // drain: tile k0 resident in LDS
    const int frow = lane & 15, fk = (lane >> 4) * 8;
    bf16x8 ah[4], bh[4], al[4], bl[4];
#pragma unroll
    for (int f = 0; f < 4; ++f) {
      ah[f] = *(const bf16x8*)&As[0][(wm * 64 + f * 16 + frow) * 32 + fk];
      bh[f] = *(const bf16x8*)&Bs[0][(wn * 64 + f * 16 + frow) * 32 + fk];
      if constexpr (NPROD == 3) {
        if (dolo) {
          al[f] = *(const bf16x8*)&As[1][(wm * 64 + f * 16 + frow) * 32 + fk];
          bl[f] = *(const bf16x8*)&Bs[1][(wn * 64 + f * 16 + frow) * 32 + fk];
        }
      }
    }
    __syncthreads();                 // all waves done reading LDS
    if (k0 + 32 < K) stage(k0 + 32); // prefetch overlaps MFMA below
#pragma unroll
    for (int fr = 0; fr < 4; ++fr)
#pragma unroll
      for (int fc = 0; fc < 4; ++fc) {
        acc[fr][fc] = __builtin_amdgcn_mfma_f32_16x16x32_bf16(ah[fr], bh[fc], acc[fr][fc], 0, 0, 0);
        if constexpr (NPROD == 3) {
          if (dolo) {
            acc[fr][fc] = __builtin_amdgcn_mfma_f32_16x16x32_bf16(ah[fr], bl[fc], acc[fr][fc], 0, 0, 0);
            acc[fr][fc] = __builtin_amdgcn_mfma_f32_16x16x32_bf16(al[fr], bh[fc], acc[fr][fc], 0, 0, 0);
          }
        }
      }
  }
  const int crow = (lane >> 4) * 4, ccol = lane & 15;
#pragma unroll
  for (int fr = 0; fr < 4; ++fr)
#pragma unroll
    for (int fc = 0; fc < 4; ++fc) {
      size_t col = bn + wn * 64 + fc * 16 + ccol;
      float badd = bias ? bias[col] : 0.0f;
#pragma unroll
      for (int i = 0; i < 4; ++i) {
        size_t row = bm + wm * 64 + fr * 16 + crow + i;
        C[row * (size_t)N + col] = acc[fr][fc][i] + badd;
      }
    }
}

// ---------------- MFMA flash attention, two-pass, swapped (S^T = K·Q) ----------------
// 1D grid 512 (XCD-chunked: 4 heads per XCD), 256 thr = 4 waves; wave owns 32 q-cols.
// K pre-scaled by 1/sqrt(128) and split hi/lo (3-product fp32-grade scores).
// RoPE-Q fused into the Q-fragment load (d^64 partner lives in ds^2 registers).
__global__ __launch_bounds__(256, 2) void attn_mfma_k(
    const float* __restrict__ qb, const ushortT* __restrict__ khi,
    const ushortT* __restrict__ klo, const ushortT* __restrict__ vt,
    const float* __restrict__ cost, const float* __restrict__ sint,
    ushortT* __restrict__ aout_bf, float* __restrict__ cur_scores) {
  const int hw = blockIdx.x;
  const int lid = (hw & 7) * 64 + (hw >> 3);          // 512 % 8 == 0: bijective
  const int h = lid >> 4, kh = h >> 2;
  const int qb0 = (15 - (lid & 15)) * 128;            // big work first within head
  const int t = threadIdx.x, lane = t & 63, wid = t >> 6;
  const int lq = lane & 15, lg = lane >> 4;

  __shared__ __align__(16) ushortT Khi_s[64 * 128];   // chunk-swizzled: c' = c ^ (k&7)
  __shared__ __align__(16) ushortT Klo_s[64 * 128];
  __shared__ __align__(16) ushortT VT_s[128 * 64];    // c' = c ^ (d&7)
  __shared__ __align__(16) ushortT p_s[4][32][72];    // per-wave P [q][k], pad 72
  __shared__ float cur_part[SEQ];

  for (int i = t; i < SEQ; i += 256) cur_part[i] = 0.0f;

  // ---- Q fragments (hi/lo) in registers; RoPE applied in-register.
  bf16x8 qh[2][4], ql[2][4];
#pragma unroll
  for (int qf = 0; qf < 2; ++qf) {
    const int qrow = qb0 + wid * 32 + qf * 16 + lq;
    const float* qpb = qb + (size_t)qrow * QKVN + h * HDIM;
    const float* cb = cost + qrow * HDIM;
    const float* sb = sint + qrow * HDIM;
    float vv[4][8];
#pragma unroll
    for (int ds = 0; ds < 4; ++ds) {
      const float* qp = qpb + ds * 32 + lg * 8;
      float4 a = *(const float4*)qp, b = *(const float4*)(qp + 4);
      vv[ds][0] = a.x; vv[ds][1] = a.y; vv[ds][2] = a.z; vv[ds][3] = a.w;
      vv[ds][4] = b.x; vv[ds][5] = b.y; vv[ds][6] = b.z; vv[ds][7] = b.w;
    }
#pragma unroll
    for (int ds = 0; ds < 4; ++ds) {
#pragma unroll
      for (int j = 0; j < 8; ++j) {
        int d = ds * 32 + lg * 8 + j;
        float rot = (ds < 2) ? -vv[ds ^ 2][j] : vv[ds ^ 2][j];
        float r = vv[ds][j] * cb[d] + rot * sb[d];
        ushortT hh = f2bf(r);
        qh[qf][ds][j] = (short)hh;
        ql[qf][ds][j] = (short)f2bf(r - bf2f(hh));
      }
    }
  }

  const int ntiles = qb0 / 64 + 2;
  const int qmaxw = qb0 + wid * 32 + 31;              // wave's largest q-row
  float m[2] = {-1e30f, -1e30f}, l[2] = {0.0f, 0.0f};

  auto stage_K = [&](int kt) {
#pragma unroll
    for (int r = 0; r < 4; ++r) {
      int cid = r * 256 + t;
      int k = cid >> 4, cp = cid & 15, c = cp ^ (k & 7);
      size_t goff = ((size_t)(kt + k) * NKVH + kh) * HDIM + c * 8;
      gload16(khi + goff, &Khi_s[cid * 8]);
      gload16(klo + goff, &Klo_s[cid * 8]);
    }
  };
  auto stage_V = [&](int kt) {
#pragma unroll
    for (int r = 0; r < 4; ++r) {
      int cid = r * 256 + t;
      int d = cid >> 3, cp = cid & 7, c = cp ^ (d & 7);
      gload16(vt + ((size_t)kh * HDIM + d) * SEQ + kt + c * 8, &VT_s[cid * 8]);
    }
  };
  auto qkt = [&](f32x4 (&acc)[4][2]) {
    __builtin_amdgcn_s_setprio(1);
#pragma unroll
    for (int ds = 0; ds < 4; ++ds)
#pragma unroll
      for (int kf = 0; kf < 4; ++kf) {
        int krow = kf * 16 + lq;
        int cp = (ds * 4 + lg) ^ (krow & 7);
        bf16x8 ah = *(const bf16x8*)&Khi_s[krow * 128 + cp * 8];
        bf16x8 al = *(const bf16x8*)&Klo_s[krow * 128 + cp * 8];
#pragma unroll
        for (int qf = 0; qf < 2; ++qf) {
          acc[kf][qf] = __builtin_amdgcn_mfma_f32_16x16x32_bf16(ah, qh[qf][ds], acc[kf][qf], 0, 0, 0);
          acc[kf][qf] = __builtin_amdgcn_mfma_f32_16x16x32_bf16(ah, ql[qf][ds], acc[kf][qf], 0, 0, 0);
          acc[kf][qf] = __builtin_amdgcn_mfma_f32_16x16x32_bf16(al, qh[qf][ds], acc[kf][qf], 0, 0, 0);
        }
      }
    __builtin_amdgcn_s_setprio(0);
  };

  // ================= PASS 1: row max + denominator =================
  stage_K(0);
  for (int tile = 0; tile < ntiles; ++tile) {
    const int kt = tile * 64;
    __syncthreads();                       // K(t) resident
    const bool active = (kt <= qmaxw);
    f32x4 acc[4][2] = {};
    if (active) qkt(acc);
    __syncthreads();                       // all LDS reads done
    if (tile + 1 < ntiles) stage_K(kt + 64);   // overlaps softmax VALU
    if (active) {
      const bool diag = (kt + 63 > qb0 + wid * 32);
#pragma unroll
      for (int qf = 0; qf < 2; ++qf) {
        const int qrow = qb0 + wid * 32 + qf * 16 + lq;
        if (diag) {
#pragma unroll
          for (int kf = 0; kf < 4; ++kf)
#pragma unroll
            for (int r = 0; r < 4; ++r)
              if (kt + kf * 16 + lg * 4 + r > qrow) acc[kf][qf][r] = -1e30f;
        }
        float tmax = -1e30f;
#pragma unroll
        for (int kf = 0; kf < 4; ++kf)
#pragma unroll
          for (int r = 0; r < 4; ++r) tmax = fmaxf(tmax, acc[kf][qf][r]);
        tmax = fmaxf(tmax, __shfl_xor(tmax, 16));
        tmax = fmaxf(tmax, __shfl_xor(tmax, 32));
        float mnew = fmaxf(m[qf], tmax);
        float ts = 0.0f;
#pragma unroll
        for (int kf = 0; kf < 4; ++kf)
#pragma unroll
          for (int r = 0; r < 4; ++r) ts += __expf(acc[kf][qf][r] - mnew);
        ts += __shfl_xor(ts, 16);
        ts += __shfl_xor(ts, 32);
        l[qf] = l[qf] * __expf(m[qf] - mnew) + ts;
        m[qf] = mnew;
      }
    }
  }

  const float rl0 = 1.0f / l[0], rl1 = 1.0f / l[1];
  f32x4 accO[8][2] = {};

  // ================= PASS 2: p -> cur (fp32) + p_s (bf16) + PV =================
  stage_K(0);
  for (int tile = 0; tile < ntiles; ++tile) {
    const int kt = tile * 64;
    __syncthreads();                       // K(t) resident; PV(t-1) done with VT_s
    stage_V(kt);                           // V(t) flies under QK^T + softmax
    const bool active = (kt <= qmaxw);
    f32x4 acc[4][2] = {};
    if (active) qkt(acc);
    __syncthreads();                       // all K-reads done
    if (tile + 1 < ntiles) stage_K(kt + 64);   // overlaps softmax VALU
    if (active) {
      const bool diag = (kt + 63 > qb0 + wid * 32);
      f32x4 csum[4];                       // per-key q-sums (over both qfrags)
#pragma unroll
      for (int kf = 0; kf < 4; ++kf)
#pragma unroll
        for (int r = 0; r < 4; ++r) csum[kf][r] = 0.0f;
#pragma unroll
      for (int qf = 0; qf < 2; ++qf) {
        const int qrow = qb0 + wid * 32 + qf * 16 + lq;
        const float rl = (qf == 0) ? rl0 : rl1;
        const float mq = m[qf];
        if (diag) {
#pragma unroll
          for (int kf = 0; kf < 4; ++kf)
#pragma unroll
            for (int r = 0; r < 4; ++r)
              if (kt + kf * 16 + lg * 4 + r > qrow) acc[kf][qf][r] = -1e30f;
        }
#pragma unroll
        for (int kf = 0; kf < 4; ++kf) {
          ushortT pk[4];
#pragma unroll
          for (int r = 0; r < 4; ++r) {
            float p = __expf(acc[kf][qf][r] - mq) * rl;
            csum[kf][r] += p;
            pk[r] = f2bf(p);
          }
          *(ushort4*)&p_s[wid][qf * 16 + lq][kf * 16 + lg * 4] = *(ushort4*)pk;
        }
      }
#pragma unroll
      for (int kf = 0; kf < 4; ++kf)
#pragma unroll
        for (int r = 0; r < 4; ++r) {
          float v = csum[kf][r];
          v += __shfl_xor(v, 1); v += __shfl_xor(v, 2);
          v += __shfl_xor(v, 4); v += __shfl_xor(v, 8);
          csum[kf][r] = v;                 // q-sum for key kf*16+lg*4+r
        }
      {
        float sel = csum[0][0];
#pragma unroll
        for (int i = 1; i < 16; ++i) {
          float v = csum[i >> 2][i & 3];
          sel = (lq == i) ? v : sel;
        }
        int ksel = (lq >> 2) * 16 + lg * 4 + (lq & 3);   // 64 distinct keys per wave
        atomicAdd(&cur_part[kt + ksel], sel);
      }
    }
    __syncthreads();                       // p_s visible; V(t) resident
    if (active) {
      __builtin_amdgcn_s_setprio(1);
#pragma unroll
      for (int ks = 0; ks < 2; ++ks) {
        bf16x8 pb[2];
#pragma unroll
        for (int qf = 0; qf < 2; ++qf)
          pb[qf] = *(const bf16x8*)&p_s[wid][qf * 16 + lq][ks * 32 + lg * 8];
#pragma unroll
        for (int fa = 0; fa < 8; ++fa) {
          int drow = fa * 16 + lq;
          int cp = (ks * 4 + lg) ^ (drow & 7);
          bf16x8 av = *(const bf16x8*)&VT_s[drow * 64 + cp * 8];
          accO[fa][0] = __builtin_amdgcn_mfma_f32_16x16x32_bf16(av, pb[0], accO[fa][0], 0, 0, 0);
          accO[fa][1] = __builtin_amdgcn_mfma_f32_16x16x32_bf16(av, pb[1], accO[fa][1], 0, 0, 0);
        }
      }
      __builtin_amdgcn_s_setprio(0);
    }
  }

  // flush cur_part -> global (one atomic per key per block)
  __syncthreads();
  const int kmax = qb0 + 128;
  for (int i = t; i < kmax; i += 256)
    atomicAdd(&cur_scores[(size_t)h * SEQ + i], cur_part[i]);

  // epilogue: O^T frag -> aout bf16 [S][NH*128]
#pragma unroll
  for (int qf = 0; qf < 2; ++qf) {
    const int qrow = qb0 + wid * 32 + qf * 16 + lq;
#pragma unroll
    for (int fa = 0; fa < 8; ++fa) {
      ushort4 w4;
      w4.x = f2bf(accO[fa][qf][0]); w4.y = f2bf(accO[fa][qf][1]);
      w4.z = f2bf(accO[fa][qf][2]); w4.w = f2bf(accO[fa][qf][3]);
      *(ushort4*)(aout_bf + (size_t)qrow * (NHEAD * HDIM) + h * HDIM + fa * 16 + lg * 4) = w4;
    }
  }
}

// ---------------- heavy-hitter top-k via exact radix-select -> mask row ----------------
__global__ __launch_bounds__(256) void topk_mask_k(const float* __restrict__ cur,
                                                   float* __restrict__ maskout) {
  const int hh = blockIdx.x;
  const int t = threadIdx.x;
  __shared__ uintT vals[SELN];
  __shared__ uintT hist[256];
  __shared__ uintT sh_prefix, sh_k;
  float* mrow = maskout + (size_t)hh * MCOLS;
  for (int c = t; c < MCOLS; c += 256)
    mrow[c] = (c >= MCOLS - RECENT) ? 1.0f : 0.0f;
  for (int i = t; i < SELN; i += 256)
    vals[i] = __float_as_uint(cur[(size_t)hh * SEQ + i]);
  if (t == 0) { sh_prefix = 0u; sh_k = HEAVY; }
  __syncthreads();
#pragma unroll
  for (int shift = 24; shift >= 0; shift -= 8) {
    if (t < 256) hist[t] = 0;
    __syncthreads();
    const uintT pre = sh_prefix;
    const uintT maskhi = (shift == 24) ? 0u : (0xFFFFFFFFu << (shift + 8));
    for (int i = t; i < SELN; i += 256) {
      uintT v = vals[i];
      if ((v & maskhi) == pre) atomicAdd(&hist[(v >> shift) & 255u], 1u);
    }
    __syncthreads();
    if (t == 0) {
      uintT k = sh_k, cum = 0; int bsel = 0;
      for (int b = 255; b >= 0; --b) {
        if (cum + hist[b] >= k) { bsel = b; break; }
        cum += hist[b];
      }
      sh_prefix = pre | ((uintT)bsel << shift);
      sh_k = k - cum;
    }
    __syncthreads();
  }
  const uintT T = sh_prefix;
  const uintT need = sh_k;
  for (int i = t; i < SELN; i += 256)
    if (vals[i] > T) mrow[i] = 1.0f;
  __syncthreads();
  if (t == 0) {
    uintT taken = 0;
    for (int i = 0; i < SELN && taken < need; ++i)
      if (vals[i] == T) { mrow[i] = 1.0f; ++taken; }
  }
}

extern "C" void kernel_launch(void* const* d_in, const int* in_sizes, int n_in,
                              void* d_out, int out_size, void* d_ws, size_t ws_size,
                              hipStream_t stream) {
  const float* hs = (const float*)d_in[0];
  const float* Wq = (const float*)d_in[1];
  const float* bq = (const float*)d_in[2];
  const float* Wk = (const float*)d_in[3];
  const float* bk = (const float*)d_in[4];
  const float* Wv = (const float*)d_in[5];
  const float* bv = (const float*)d_in[6];
  const float* Wo = (const float*)d_in[7];
  float* out = (float*)d_out;
  float* maskout = out + (size_t)SEQ * HID;

  char* w = (char*)d_ws;
  auto alloc = [&](size_t bytes) { char* p = w; w += (bytes + 255) & ~(size_t)255; return p; };
  float*   fused  = (float*)alloc((size_t)SEQ * QKVN * 4);        // QKV projections
  float*   cost   = (float*)alloc((size_t)SEQ * HDIM * 4);
  float*   sint   = (float*)alloc((size_t)SEQ * HDIM * 4);
  float*   cur    = (float*)alloc((size_t)NHEAD * SEQ * 4);
  float*   biasf  = (float*)alloc((size_t)QKVN * 4);
  ushortT* hshi   = (ushortT*)alloc((size_t)SEQ * HID * 2);
  ushortT* hslo   = (ushortT*)alloc((size_t)SEQ * HID * 2);
  ushortT* whi    = (ushortT*)alloc((size_t)QKVN * HID * 2);
  ushortT* wlo    = (ushortT*)alloc((size_t)QKVN * HID * 2);
  ushortT* wohi   = (ushortT*)alloc((size_t)HID * HID * 2);
  // aliases: consumed-before-written ordering makes these safe
  ushortT* aouthi = hshi;                                  // attn out (after GEMM read hshi)
  ushortT* khi_g  = hslo;                                  // 2048*1024 each
  ushortT* klo_g  = hslo + (size_t)SEQ * NKVH * HDIM;
  ushortT* vt_g   = hslo + (size_t)2 * SEQ * NKVH * HDIM;

  hipLaunchKernelGGL(rope_tables_k, dim3(SEQ), dim3(HDIM), 0, stream, cost, sint);

  {
    int n4;
    n4 = SEQ * HID / 4;
    hipLaunchKernelGGL(convert_split_k, dim3((n4 + 255) / 256), dim3(256), 0, stream, hs, hshi, hslo, n4);
    n4 = QKVN * HID / 4;                      // Wq|Wk|Wv merged split
    hipLaunchKernelGGL(convert_wqkv_k, dim3((n4 + 255) / 256), dim3(256), 0, stream,
                       Wq, Wk, Wv, whi, wlo);
    n4 = HID * HID / 4;
    hipLaunchKernelGGL(convert_hi_k, dim3((n4 + 255) / 256), dim3(256), 0, stream, Wo, wohi, n4);
    hipLaunchKernelGGL(fuse_bias_k, dim3(QKVN / 256), dim3(256), 0, stream, bq, bk, bv, biasf);
  }

  // fused QKV projection (split-bf16, 3-product for Q/K cols, 1-product for V cols)
  hipLaunchKernelGGL((gemm_mfma_nt<3>), dim3(QKVN / 128, SEQ / 128), dim3(256), 0, stream,
                     hshi, hslo, whi, wlo, biasf, fused, SEQ, QKVN, HID, 5120);

  hipLaunchKernelGGL(rope_k_split_k, dim3(SEQ, NKVH), dim3(HDIM), 0, stream, fused, cost, sint,
                     khi_g, klo_g);
  hipLaunchKernelGGL(transpose_v_k, dim3(NKVH * HDIM * (SEQ / 8) / 256), dim3(256), 0, stream,
                     fused, vt_g);

  hipMemsetAsync(cur, 0, (size_t)NHEAD * SEQ * sizeof(float), stream);

  hipLaunchKernelGGL(attn_mfma_k, dim3((SEQ / 128) * NHEAD), dim3(256), 0, stream,
                     fused, khi_g, klo_g, vt_g, cost, sint, aouthi, cur);

  // out projection (plain bf16), natural 2D dispatch
  hipLaunchKernelGGL((gemm_mfma_nt<1>), dim3(HID / 128, SEQ / 128), dim3(256), 0, stream,
                     aouthi, (const ushortT*)nullptr, wohi, (const ushortT*)nullptr,
                     (const float*)nullptr, out, SEQ, HID, HID, 0);

  hipLaunchKernelGGL(topk_mask_k, dim3(NHEAD), dim3(256), 0, stream, cur, maskout);
}

// Round 10
// 731.456 us; speedup vs baseline: 1.8301x; 1.0360x over previous
//
#include <hip/hip_runtime.h>
#include <hip/hip_bf16.h>
#include <cfloat>
#include <math.h>

#define SEQ    2048
#define HID    4096
#define NHEAD  32
#define NKVH   8
#define HDIM   128
#define QKVN   6144            /* fused projection width: 4096 Q + 1024 K + 1024 V */
#define HEAVY  204
#define RECENT 204
#define SELN   (SEQ - RECENT)   /* 1844 */
#define MCOLS  (SEQ + 1)        /* 2049 */

typedef unsigned short ushortT;
typedef unsigned int uintT;

using bf16x8 = __attribute__((ext_vector_type(8))) short;
using f32x4  = __attribute__((ext_vector_type(4))) float;

// ---------------- helpers ----------------
__device__ __forceinline__ ushortT f2bf(float x) {
  uintT u = __float_as_uint(x);
  uintT r = (u + 0x7fffu + ((u >> 16) & 1u)) >> 16;   // RNE
  return (ushortT)r;
}
__device__ __forceinline__ float bf2f(ushortT h) {
  return __uint_as_float((uintT)h << 16);
}
__device__ __forceinline__ void gload16(const void* g, void* l) {
  __builtin_amdgcn_global_load_lds((const __attribute__((address_space(1))) void*)g,
                                   (__attribute__((address_space(3))) void*)l, 16, 0, 0);
}

// ---------------- RoPE tables (match numpy fp32 pipeline) ----------------
// inv_freq via double pow (correctly-rounded, matches numpy); trig in float
// (sinf/cosf ~2 ulp vs numpy ~1.5 ulp: table diff ~3e-7 << 2.5e-4 top-k gaps).
__global__ void rope_tables_k(float* __restrict__ cost, float* __restrict__ sint) {
  int s = blockIdx.x, d = threadIdx.x;
  int f = d & 63;
  float powv = (float)pow(10000.0, (double)f / 64.0);
  float invf = 1.0f / powv;
  float ang  = (float)s * invf;
  cost[s * HDIM + d] = cosf(ang);
  sint[s * HDIM + d] = sinf(ang);
}

// ---------------- RoPE-K + scale + hi/lo split (reads fused, writes khi/klo) --------
__global__ void rope_k_split_k(const float* __restrict__ fused, const float* __restrict__ cost,
                               const float* __restrict__ sint, ushortT* __restrict__ khi,
                               ushortT* __restrict__ klo) {
  int s = blockIdx.x, kh = blockIdx.y, d = threadIdx.x;
  const float* row = fused + (size_t)s * QKVN + 4096 + kh * HDIM;
  float v  = row[d];
  float vp = row[d ^ 64];
  float rot = (d < 64) ? -vp : vp;
  float r = (v * cost[s * HDIM + d] + rot * sint[s * HDIM + d]) * 0.08838834764831845f;
  ushortT hh = f2bf(r);
  size_t o = ((size_t)s * NKVH + kh) * HDIM + d;
  khi[o] = hh;
  klo[o] = f2bf(r - bf2f(hh));
}

// ---------------- fp32 -> bf16 hi/lo split conversion ----------------
__global__ void convert_split_k(const float* __restrict__ src, ushortT* __restrict__ hi,
                                ushortT* __restrict__ lo, int n4) {
  int i = blockIdx.x * blockDim.x + threadIdx.x;
  if (i >= n4) return;
  float4 v = ((const float4*)src)[i];
  ushort4 h, l;
  h.x = f2bf(v.x); l.x = f2bf(v.x - bf2f(h.x));
  h.y = f2bf(v.y); l.y = f2bf(v.y - bf2f(h.y));
  h.z = f2bf(v.z); l.z = f2bf(v.z - bf2f(h.z));
  h.w = f2bf(v.w); l.w = f2bf(v.w - bf2f(h.w));
  ((ushort4*)hi)[i] = h;
  ((ushort4*)lo)[i] = l;
}
// merged Wq|Wk|Wv split into fused layout rows [0,4096)|[4096,5120)|[5120,6144)
// V rows (>=5120) skip the lo write: their lo limb is never read (1-product V path).
__global__ void convert_wqkv_k(const float* __restrict__ Wq, const float* __restrict__ Wk,
                               const float* __restrict__ Wv, ushortT* __restrict__ hi,
                               ushortT* __restrict__ lo) {
  int i = blockIdx.x * 256 + threadIdx.x;      // float4 index
  if (i >= QKVN * HID / 4) return;
  int e = i * 4;
  int row = e >> 12;
  const float* src;
  if (row < 4096)      src = Wq + e;
  else if (row < 5120) src = Wk + (e - (4096 << 12));
  else                 src = Wv + (e - (5120 << 12));
  float4 v = *(const float4*)src;
  ushort4 h, l;
  h.x = f2bf(v.x); l.x = f2bf(v.x - bf2f(h.x));
  h.y = f2bf(v.y); l.y = f2bf(v.y - bf2f(h.y));
  h.z = f2bf(v.z); l.z = f2bf(v.z - bf2f(h.z));
  h.w = f2bf(v.w); l.w = f2bf(v.w - bf2f(h.w));
  ((ushort4*)hi)[i] = h;
  if (row < 5120) ((ushort4*)lo)[i] = l;
}
__global__ void convert_hi_k(const float* __restrict__ src, ushortT* __restrict__ hi, int n4) {
  int i = blockIdx.x * blockDim.x + threadIdx.x;
  if (i >= n4) return;
  float4 v = ((const float4*)src)[i];
  ushort4 h;
  h.x = f2bf(v.x); h.y = f2bf(v.y); h.z = f2bf(v.z); h.w = f2bf(v.w);
  ((ushort4*)hi)[i] = h;
}
__global__ void fuse_bias_k(const float* __restrict__ bq, const float* __restrict__ bk,
                            const float* __restrict__ bv, float* __restrict__ bias) {
  int i = blockIdx.x * 256 + threadIdx.x;
  if (i < 4096) bias[i] = bq[i];
  else if (i < 5120) bias[i] = bk[i - 4096];
  else if (i < QKVN) bias[i] = bv[i - 5120];
}

// ---------------- V transpose: fused V region fp32 -> vt [NKVH][128][S] bf16 --------
__global__ __launch_bounds__(256) void transpose_v_k(const float* __restrict__ fused,
                                                     ushortT* __restrict__ vt) {
  int g = blockIdx.x * 256 + threadIdx.x;
  int d = g & 127;
  int rest = g >> 7;
  int sblk = rest & (SEQ / 8 - 1);
  int kh = rest >> 8;
  ushortT tmp[8];
#pragma unroll
  for (int i = 0; i < 8; ++i) {
    float v = fused[(size_t)(sblk * 8 + i) * QKVN + 5120 + kh * HDIM + d];
    tmp[i] = f2bf(v);
  }
  ushortT* o = vt + ((size_t)kh * HDIM + d) * SEQ + sblk * 8;
  *(ushort4*)o = *(ushort4*)tmp;
  *(ushort4*)(o + 4) = *(ushort4*)&tmp[4];
}

// ---------------- bf16 MFMA NT GEMM (split-precision capable, prefetch) ----------------
// Proven R5 structure (909 TF): 128x128 tile, BK=32, 4 waves, natural 2D dispatch.
// Blocks with bn >= split_cols use 1-product (hi·hi) only: V columns need no split.
template<int NPROD>
__global__ __launch_bounds__(256, NPROD == 3 ? 3 : 4) void gemm_mfma_nt(
    const ushortT* __restrict__ Ahi, const ushortT* __restrict__ Alo,
    const ushortT* __restrict__ Bhi, const ushortT* __restrict__ Blo,
    const float* __restrict__ bias, float* __restrict__ C,
    int M, int N, int K, int split_cols) {
  constexpr int NB = (NPROD == 3) ? 2 : 1;
  __shared__ __align__(16) ushortT As[NB][128 * 32];
  __shared__ __align__(16) ushortT Bs[NB][128 * 32];
  const int t = threadIdx.x;
  const int lane = t & 63, wid = t >> 6;
  const int wm = wid >> 1, wn = wid & 1;
  const size_t bm = (size_t)blockIdx.y * 128, bn = (size_t)blockIdx.x * 128;
  const bool dolo = (NPROD == 3) && ((int)bn < split_cols);
  f32x4 acc[4][4] = {};
  const int r0 = t >> 2, kc0 = (t & 3) * 8;

  auto stage = [&](int k0) {
    const ushortT* ga = Ahi + (bm + r0) * (size_t)K + k0 + kc0;
    gload16(ga, &As[0][r0 * 32 + kc0]);
    gload16(ga + (size_t)64 * K, &As[0][(r0 + 64) * 32 + kc0]);
    const ushortT* gb = Bhi + (bn + r0) * (size_t)K + k0 + kc0;
    gload16(gb, &Bs[0][r0 * 32 + kc0]);
    gload16(gb + (size_t)64 * K, &Bs[0][(r0 + 64) * 32 + kc0]);
    if constexpr (NPROD == 3) {
      if (dolo) {
        const ushortT* ga2 = Alo + (bm + r0) * (size_t)K + k0 + kc0;
        gload16(ga2, &As[1][r0 * 32 + kc0]);
        gload16(ga2 + (size_t)64 * K, &As[1][(r0 + 64) * 32 + kc0]);
        const ushortT* gb2 = Blo + (bn + r0) * (size_t)K + k0 + kc0;
        gload16(gb2, &Bs[1][r0 * 32 + kc0]);
        gload16(gb2 + (size_t)64 * K, &Bs[1][(r0 + 64) * 32 + kc0]);
      }
    }
  };

  stage(0);
  for (int k0 = 0; k0 < K; k0 += 32) {
    __syncthreads();                 // drain: tile k0 resident in LDS
    const int frow = lane & 15, fk = (lane >> 4) * 8;
    bf16x8 ah[4], bh[4], al[4], bl[4];
#pragma unroll
    for (int f = 0; f < 4; ++f) {
      ah[f] = *(const bf16x8*)&As[0][(wm * 64 + f * 16 + frow) * 32 + fk];
      bh[f] = *(const bf16x8*)&Bs[0][(wn * 64 + f * 16 + frow) * 32 + fk];
      if constexpr (NPROD == 3) {
        if (dolo) {
          al[f] = *(const bf16x8*)&As[1][(wm * 64 + f * 16 + frow) * 32 + fk];
          bl[f] = *(const bf16x8*)&Bs[1][(wn * 64 + f * 16 + frow) * 32 + fk];
        }
      }
    }
    __syncthreads();                 // all waves done reading LDS
    if (k0 + 32 < K) stage(k0 + 32); // prefetch overlaps MFMA below
#pragma unroll
    for (int fr = 0; fr < 4; ++fr)
#pragma unroll
      for (int fc = 0; fc < 4; ++fc) {
        acc[fr][fc] = __builtin_amdgcn_mfma_f32_16x16x32_bf16(ah[fr], bh[fc], acc[fr][fc], 0, 0, 0);
        if constexpr (NPROD == 3) {
          if (dolo) {
            acc[fr][fc] = __builtin_amdgcn_mfma_f32_16x16x32_bf16(ah[fr], bl[fc], acc[fr][fc], 0, 0, 0);
            acc[fr][fc] = __builtin_amdgcn_mfma_f32_16x16x32_bf16(al[fr], bh[fc], acc[fr][fc], 0, 0, 0);
          }
        }
      }
  }
  const int crow = (lane >> 4) * 4, ccol = lane & 15;
#pragma unroll
  for (int fr = 0; fr < 4; ++fr)
#pragma unroll
    for (int fc = 0; fc < 4; ++fc) {
      size_t col = bn + wn * 64 + fc * 16 + ccol;
      float badd = bias ? bias[col] : 0.0f;
#pragma unroll
      for (int i = 0; i < 4; ++i) {
        size_t row = bm + wm * 64 + fr * 16 + crow + i;
        C[row * (size_t)N + col] = acc[fr][fc][i] + badd;
      }
    }
}

// ---------------- MFMA flash attention, two-pass, swapped (S^T = K·Q) ----------------
// 1D grid 512 (XCD-chunked: 4 heads per XCD), 256 thr = 4 waves; wave owns 32 q-cols.
// K pre-scaled by 1/sqrt(128) and split hi/lo (3-product fp32-grade scores).
// RoPE-Q fused into the Q-fragment load (d^64 partner lives in ds^2 registers).
__global__ __launch_bounds__(256, 2) void attn_mfma_k(
    const float* __restrict__ qb, const ushortT* __restrict__ khi,
    const ushortT* __restrict__ klo, const ushortT* __restrict__ vt,
    const float* __restrict__ cost, const float* __restrict__ sint,
    ushortT* __restrict__ aout_bf, float* __restrict__ cur_scores) {
  const int hw = blockIdx.x;
  const int lid = (hw & 7) * 64 + (hw >> 3);          // 512 % 8 == 0: bijective
  const int h = lid >> 4, kh = h >> 2;
  const int qb0 = (15 - (lid & 15)) * 128;            // big work first within head
  const int t = threadIdx.x, lane = t & 63, wid = t >> 6;
  const int lq = lane & 15, lg = lane >> 4;

  __shared__ __align__(16) ushortT Khi_s[64 * 128];   // chunk-swizzled: c' = c ^ (k&7)
  __shared__ __align__(16) ushortT Klo_s[64 * 128];
  __shared__ __align__(16) ushortT VT_s[128 * 64];    // c' = c ^ (d&7)
  __shared__ __align__(16) ushortT p_s[4][32][72];    // per-wave P [q][k], pad 72
  __shared__ float cur_part[SEQ];

  for (int i = t; i < SEQ; i += 256) cur_part[i] = 0.0f;

  // ---- Q fragments (hi/lo) in registers; RoPE applied in-register.
  bf16x8 qh[2][4], ql[2][4];
#pragma unroll
  for (int qf = 0; qf < 2; ++qf) {
    const int qrow = qb0 + wid * 32 + qf * 16 + lq;
    const float* qpb = qb + (size_t)qrow * QKVN + h * HDIM;
    const float* cb = cost + qrow * HDIM;
    const float* sb = sint + qrow * HDIM;
    float vv[4][8];
#pragma unroll
    for (int ds = 0; ds < 4; ++ds) {
      const float* qp = qpb + ds * 32 + lg * 8;
      float4 a = *(const float4*)qp, b = *(const float4*)(qp + 4);
      vv[ds][0] = a.x; vv[ds][1] = a.y; vv[ds][2] = a.z; vv[ds][3] = a.w;
      vv[ds][4] = b.x; vv[ds][5] = b.y; vv[ds][6] = b.z; vv[ds][7] = b.w;
    }
#pragma unroll
    for (int ds = 0; ds < 4; ++ds) {
#pragma unroll
      for (int j = 0; j < 8; ++j) {
        int d = ds * 32 + lg * 8 + j;
        float rot = (ds < 2) ? -vv[ds ^ 2][j] : vv[ds ^ 2][j];
        float r = vv[ds][j] * cb[d] + rot * sb[d];
        ushortT hh = f2bf(r);
        qh[qf][ds][j] = (short)hh;
        ql[qf][ds][j] = (short)f2bf(r - bf2f(hh));
      }
    }
  }

  const int ntiles = qb0 / 64 + 2;
  const int qmaxw = qb0 + wid * 32 + 31;              // wave's largest q-row
  float m[2] = {-1e30f, -1e30f}, l[2] = {0.0f, 0.0f};

  auto stage_K = [&](int kt) {
#pragma unroll
    for (int r = 0; r < 4; ++r) {
      int cid = r * 256 + t;
      int k = cid >> 4, cp = cid & 15, c = cp ^ (k & 7);
      size_t goff = ((size_t)(kt + k) * NKVH + kh) * HDIM + c * 8;
      gload16(khi + goff, &Khi_s[cid * 8]);
      gload16(klo + goff, &Klo_s[cid * 8]);
    }
  };
  auto stage_V = [&](int kt) {
#pragma unroll
    for (int r = 0; r < 4; ++r) {
      int cid = r * 256 + t;
      int d = cid >> 3, cp = cid & 7, c = cp ^ (d & 7);
      gload16(vt + ((size_t)kh * HDIM + d) * SEQ + kt + c * 8, &VT_s[cid * 8]);
    }
  };
  auto qkt = [&](f32x4 (&acc)[4][2]) {
    __builtin_amdgcn_s_setprio(1);
#pragma unroll
    for (int ds = 0; ds < 4; ++ds)
#pragma unroll
      for (int kf = 0; kf < 4; ++kf) {
        int krow = kf * 16 + lq;
        int cp = (ds * 4 + lg) ^ (krow & 7);
        bf16x8 ah = *(const bf16x8*)&Khi_s[krow * 128 + cp * 8];
        bf16x8 al = *(const bf16x8*)&Klo_s[krow * 128 + cp * 8];
#pragma unroll
        for (int qf = 0; qf < 2; ++qf) {
          acc[kf][qf] = __builtin_amdgcn_mfma_f32_16x16x32_bf16(ah, qh[qf][ds], acc[kf][qf], 0, 0, 0);
          acc[kf][qf] = __builtin_amdgcn_mfma_f32_16x16x32_bf16(ah, ql[qf][ds], acc[kf][qf], 0, 0, 0);
          acc[kf][qf] = __builtin_amdgcn_mfma_f32_16x16x32_bf16(al, qh[qf][ds], acc[kf][qf], 0, 0, 0);
        }
      }
    __builtin_amdgcn_s_setprio(0);
  };

  // ================= PASS 1: row max + denominator =================
  stage_K(0);
  for (int tile = 0; tile < ntiles; ++tile) {
    const int kt = tile * 64;
    __syncthreads();                       // K(t) resident
    const bool active = (kt <= qmaxw);
    f32x4 acc[4][2] = {};
    if (active) qkt(acc);
    __syncthreads();                       // all LDS reads done
    if (tile + 1 < ntiles) stage_K(kt + 64);   // overlaps softmax VALU
    if (active) {
      const bool diag = (kt + 63 > qb0 + wid * 32);
#pragma unroll
      for (int qf = 0; qf < 2; ++qf) {
        const int qrow = qb0 + wid * 32 + qf * 16 + lq;
        if (diag) {
#pragma unroll
          for (int kf = 0; kf < 4; ++kf)
#pragma unroll
            for (int r = 0; r < 4; ++r)
              if (kt + kf * 16 + lg * 4 + r > qrow) acc[kf][qf][r] = -1e30f;
        }
        float tmax = -1e30f;
#pragma unroll
        for (int kf = 0; kf < 4; ++kf)
#pragma unroll
          for (int r = 0; r < 4; ++r) tmax = fmaxf(tmax, acc[kf][qf][r]);
        tmax = fmaxf(tmax, __shfl_xor(tmax, 16));
        tmax = fmaxf(tmax, __shfl_xor(tmax, 32));
        float mnew = fmaxf(m[qf], tmax);
        float ts = 0.0f;
#pragma unroll
        for (int kf = 0; kf < 4; ++kf)
#pragma unroll
          for (int r = 0; r < 4; ++r) ts += __expf(acc[kf][qf][r] - mnew);
        ts += __shfl_xor(ts, 16);
        ts += __shfl_xor(ts, 32);
        l[qf] = l[qf] * __expf(m[qf] - mnew) + ts;
        m[qf] = mnew;
      }
    }
  }

  const float rl0 = 1.0f / l[0], rl1 = 1.0f / l[1];
  f32x4 accO[8][2] = {};

  // ================= PASS 2: p -> cur (fp32) + p_s (bf16) + PV =================
  stage_K(0);
  for (int tile = 0; tile < ntiles; ++tile) {
    const int kt = tile * 64;
    __syncthreads();                       // K(t) resident; PV(t-1) done with VT_s
    stage_V(kt);                           // V(t) flies under QK^T + softmax
    const bool active = (kt <= qmaxw);
    f32x4 acc[4][2] = {};
    if (active) qkt(acc);
    __syncthreads();                       // all K-reads done
    if (tile + 1 < ntiles) stage_K(kt + 64);   // overlaps softmax VALU
    if (active) {
      const bool diag = (kt + 63 > qb0 + wid * 32);
      f32x4 csum[4];                       // per-key q-sums (over both qfrags)
#pragma unroll
      for (int kf = 0; kf < 4; ++kf)
#pragma unroll
        for (int r = 0; r < 4; ++r) csum[kf][r] = 0.0f;
#pragma unroll
      for (int qf = 0; qf < 2; ++qf) {
        const int qrow = qb0 + wid * 32 + qf * 16 + lq;
        const float rl = (qf == 0) ? rl0 : rl1;
        const float mq = m[qf];
        if (diag) {
#pragma unroll
          for (int kf = 0; kf < 4; ++kf)
#pragma unroll
            for (int r = 0; r < 4; ++r)
              if (kt + kf * 16 + lg * 4 + r > qrow) acc[kf][qf][r] = -1e30f;
        }
#pragma unroll
        for (int kf = 0; kf < 4; ++kf) {
          ushortT pk[4];
#pragma unroll
          for (int r = 0; r < 4; ++r) {
            float p = __expf(acc[kf][qf][r] - mq) * rl;
            csum[kf][r] += p;
            pk[r] = f2bf(p);
          }
          *(ushort4*)&p_s[wid][qf * 16 + lq][kf * 16 + lg * 4] = *(ushort4*)pk;
        }
      }
#pragma unroll
      for (int kf = 0; kf < 4; ++kf)
#pragma unroll
        for (int r = 0; r < 4; ++r) {
          float v = csum[kf][r];
          v += __shfl_xor(v, 1); v += __shfl_xor(v, 2);
          v += __shfl_xor(v, 4); v += __shfl_xor(v, 8);
          csum[kf][r] = v;                 // q-sum for key kf*16+lg*4+r
        }
      {
        float sel = csum[0][0];
#pragma unroll
        for (int i = 1; i < 16; ++i) {
          float v = csum[i >> 2][i & 3];
          sel = (lq == i) ? v : sel;
        }
        int ksel = (lq >> 2) * 16 + lg * 4 + (lq & 3);   // 64 distinct keys per wave
        atomicAdd(&cur_part[kt + ksel], sel);
      }
    }
    __syncthreads();                       // p_s visible; V(t) resident
    if (active) {
      __builtin_amdgcn_s_setprio(1);
#pragma unroll
      for (int ks = 0; ks < 2; ++ks) {
        bf16x8 pb[2];
#pragma unroll
        for (int qf = 0; qf < 2; ++qf)
          pb[qf] = *(const bf16x8*)&p_s[wid][qf * 16 + lq][ks * 32 + lg * 8];
#pragma unroll
        for (int fa = 0; fa < 8; ++fa) {
          int drow = fa * 16 + lq;
          int cp = (ks * 4 + lg) ^ (drow & 7);
          bf16x8 av = *(const bf16x8*)&VT_s[drow * 64 + cp * 8];
          accO[fa][0] = __builtin_amdgcn_mfma_f32_16x16x32_bf16(av, pb[0], accO[fa][0], 0, 0, 0);
          accO[fa][1] = __builtin_amdgcn_mfma_f32_16x16x32_bf16(av, pb[1], accO[fa][1], 0, 0, 0);
        }
      }
      __builtin_amdgcn_s_setprio(0);
    }
  }

  // flush cur_part -> global (one atomic per key per block)
  __syncthreads();
  const int kmax = qb0 + 128;
  for (int i = t; i < kmax; i += 256)
    atomicAdd(&cur_scores[(size_t)h * SEQ + i], cur_part[i]);

  // epilogue: O^T frag -> aout bf16 [S][NH*128]
#pragma unroll
  for (int qf = 0; qf < 2; ++qf) {
    const int qrow = qb0 + wid * 32 + qf * 16 + lq;
#pragma unroll
    for (int fa = 0; fa < 8; ++fa) {
      ushort4 w4;
      w4.x = f2bf(accO[fa][qf][0]); w4.y = f2bf(accO[fa][qf][1]);
      w4.z = f2bf(accO[fa][qf][2]); w4.w = f2bf(accO[fa][qf][3]);
      *(ushort4*)(aout_bf + (size_t)qrow * (NHEAD * HDIM) + h * HDIM + fa * 16 + lg * 4) = w4;
    }
  }
}

// ---------------- heavy-hitter top-k via exact radix-select -> mask row ----------------
__global__ __launch_bounds__(256) void topk_mask_k(const float* __restrict__ cur,
                                                   float* __restrict__ maskout) {
  const int hh = blockIdx.x;
  const int t = threadIdx.x;
  __shared__ uintT vals[SELN];
  __shared__ uintT hist[256];
  __shared__ uintT sh_prefix, sh_k;
  float* mrow = maskout + (size_t)hh * MCOLS;
  for (int c = t; c < MCOLS; c += 256)
    mrow[c] = (c >= MCOLS - RECENT) ? 1.0f : 0.0f;
  for (int i = t; i < SELN; i += 256)
    vals[i] = __float_as_uint(cur[(size_t)hh * SEQ + i]);
  if (t == 0) { sh_prefix = 0u; sh_k = HEAVY; }
  __syncthreads();
#pragma unroll
  for (int shift = 24; shift >= 0; shift -= 8) {
    if (t < 256) hist[t] = 0;
    __syncthreads();
    const uintT pre = sh_prefix;
    const uintT maskhi = (shift == 24) ? 0u : (0xFFFFFFFFu << (shift + 8));
    for (int i = t; i < SELN; i += 256) {
      uintT v = vals[i];
      if ((v & maskhi) == pre) atomicAdd(&hist[(v >> shift) & 255u], 1u);
    }
    __syncthreads();
    if (t == 0) {
      uintT k = sh_k, cum = 0; int bsel = 0;
      for (int b = 255; b >= 0; --b) {
        if (cum + hist[b] >= k) { bsel = b; break; }
        cum += hist[b];
      }
      sh_prefix = pre | ((uintT)bsel << shift);
      sh_k = k - cum;
    }
    __syncthreads();
  }
  const uintT T = sh_prefix;
  const uintT need = sh_k;
  for (int i = t; i < SELN; i += 256)
    if (vals[i] > T) mrow[i] = 1.0f;
  // parallel stable fill of == T in ascending index order (chunk count + scan)
  __shared__ uintT ccnt[256];
  const int CH = (SELN + 255) / 256;
  const int i0 = t * CH, i1 = (i0 + CH < SELN) ? i0 + CH : SELN;
  uintT cnt = 0;
  for (int i = i0; i < i1; ++i) cnt += (vals[i] == T) ? 1u : 0u;
  ccnt[t] = cnt;
  __syncthreads();
  for (int off = 1; off < 256; off <<= 1) {
    uintT v = (t >= off) ? ccnt[t - off] : 0u;
    __syncthreads();
    ccnt[t] += v;
    __syncthreads();
  }
  uintT taken = ccnt[t] - cnt;               // exclusive prefix of == T before chunk
  for (int i = i0; i < i1 && taken < need; ++i)
    if (vals[i] == T) { mrow[i] = 1.0f; ++taken; }
}

extern "C" void kernel_launch(void* const* d_in, const int* in_sizes, int n_in,
                              void* d_out, int out_size, void* d_ws, size_t ws_size,
                              hipStream_t stream) {
  const float* hs = (const float*)d_in[0];
  const float* Wq = (const float*)d_in[1];
  const float* bq = (const float*)d_in[2];
  const float* Wk = (const float*)d_in[3];
  const float* bk = (const float*)d_in[4];
  const float* Wv = (const float*)d_in[5];
  const float* bv = (const float*)d_in[6];
  const float* Wo = (const float*)d_in[7];
  float* out = (float*)d_out;
  float* maskout = out + (size_t)SEQ * HID;

  char* w = (char*)d_ws;
  auto alloc = [&](size_t bytes) { char* p = w; w += (bytes + 255) & ~(size_t)255; return p; };
  float*   fused  = (float*)alloc((size_t)SEQ * QKVN * 4);        // QKV projections
  float*   cost   = (float*)alloc((size_t)SEQ * HDIM * 4);
  float*   sint   = (float*)alloc((size_t)SEQ * HDIM * 4);
  float*   cur    = (float*)alloc((size_t)NHEAD * SEQ * 4);
  float*   biasf  = (float*)alloc((size_t)QKVN * 4);
  ushortT* hshi   = (ushortT*)alloc((size_t)SEQ * HID * 2);
  ushortT* hslo   = (ushortT*)alloc((size_t)SEQ * HID * 2);
  ushortT* whi    = (ushortT*)alloc((size_t)QKVN * HID * 2);
  ushortT* wlo    = (ushortT*)alloc((size_t)QKVN * HID * 2);
  ushortT* wohi   = (ushortT*)alloc((size_t)HID * HID * 2);
  // aliases: consumed-before-written ordering makes these safe
  ushortT* aouthi = hshi;                                  // attn out (after GEMM read hshi)
  ushortT* khi_g  = hslo;                                  // 2048*1024 each
  ushortT* klo_g  = hslo + (size_t)SEQ * NKVH * HDIM;
  ushortT* vt_g   = hslo + (size_t)2 * SEQ * NKVH * HDIM;

  hipLaunchKernelGGL(rope_tables_k, dim3(SEQ), dim3(HDIM), 0, stream, cost, sint);

  {
    int n4;
    n4 = SEQ * HID / 4;
    hipLaunchKernelGGL(convert_split_k, dim3((n4 + 255) / 256), dim3(256), 0, stream, hs, hshi, hslo, n4);
    n4 = QKVN * HID / 4;                      // Wq|Wk|Wv merged split
    hipLaunchKernelGGL(convert_wqkv_k, dim3((n4 + 255) / 256), dim3(256), 0, stream,
                       Wq, Wk, Wv, whi, wlo);
    n4 = HID * HID / 4;
    hipLaunchKernelGGL(convert_hi_k, dim3((n4 + 255) / 256), dim3(256), 0, stream, Wo, wohi, n4);
    hipLaunchKernelGGL(fuse_bias_k, dim3(QKVN / 256), dim3(256), 0, stream, bq, bk, bv, biasf);
  }

  // fused QKV projection (split-bf16, 3-product for Q/K cols, 1-product for V cols)
  hipLaunchKernelGGL((gemm_mfma_nt<3>), dim3(QKVN / 128, SEQ / 128), dim3(256), 0, stream,
                     hshi, hslo, whi, wlo, biasf, fused, SEQ, QKVN, HID, 5120);

  hipLaunchKernelGGL(rope_k_split_k, dim3(SEQ, NKVH), dim3(HDIM), 0, stream, fused, cost, sint,
                     khi_g, klo_g);
  hipLaunchKernelGGL(transpose_v_k, dim3(NKVH * HDIM * (SEQ / 8) / 256), dim3(256), 0, stream,
                     fused, vt_g);

  hipMemsetAsync(cur, 0, (size_t)NHEAD * SEQ * sizeof(float), stream);

  hipLaunchKernelGGL(attn_mfma_k, dim3((SEQ / 128) * NHEAD), dim3(256), 0, stream,
                     fused, khi_g, klo_g, vt_g, cost, sint, aouthi, cur);

  // out projection (plain bf16), natural 2D dispatch
  hipLaunchKernelGGL((gemm_mfma_nt<1>), dim3(HID / 128, SEQ / 128), dim3(256), 0, stream,
                     aouthi, (const ushortT*)nullptr, wohi, (const ushortT*)nullptr,
                     (const float*)nullptr, out, SEQ, HID, HID, 0);

  hipLaunchKernelGGL(topk_mask_k, dim3(NHEAD), dim3(256), 0, stream, cur, maskout);
}